// Round 2
// baseline (6889.622 us; speedup 1.0000x reference)
//
#include <hip/hip_runtime.h>
#include <stdint.h>

#define SEQB 512
#define BATCH 32
#define EDIM 256
#define HIDN 256
#define HH2 512
#define RDIM 128
#define NEnt 64
#define NSt 64
#define NNODE 128
#define NHELP 112
#define HPG 14          // helpers per arrive-group (112/8)
#define NROWS 3584      // 1536 (U0) + 1536 (U1) + 512 (Uf)
#define TERMEVT 0xFFFFFFFFu
#define SCOPE_AGENT __HIP_MEMORY_SCOPE_AGENT

static __device__ __forceinline__ float sigm(float x) { return 1.0f / (1.0f + __expf(-x)); }
static __device__ __forceinline__ float tanh_f(float x) { return 1.0f - 2.0f / (__expf(2.0f * x) + 1.0f); }

// ---------------------------------------------------------------------------
// Tiled fp32 GEMM: C[m][n] = sum_k Arow(m)[k] * Brow(n)[k] (+ bias[n])
// 128x128 tile, 256 threads, 8x8 per thread (4+4 split), register prefetch.
// ---------------------------------------------------------------------------
template<int GATHER>
__global__ __launch_bounds__(256) void gemm_tn(
    const float* __restrict__ A, const int* __restrict__ gidx, const float* __restrict__ gtab,
    const float* __restrict__ B0, const float* __restrict__ B1, int nsplitB,
    const float* __restrict__ bias0, const float* __restrict__ bias1, int nsplitBias,
    float* __restrict__ C, int M, int N, int K)
{
  __shared__ float As[16][132];
  __shared__ float Bs[16][132];
  const int tid = threadIdx.x;
  const int m0 = blockIdx.y * 128, n0 = blockIdx.x * 128;

  const int lrow = tid >> 1;            // 0..127
  const int lk   = (tid & 1) * 8;       // 0 or 8
  const float* arow;
  if (GATHER) arow = gtab + (size_t)gidx[m0 + lrow] * K + lk;
  else        arow = A + (size_t)(m0 + lrow) * K + lk;
  const int bn = n0 + lrow;
  const float* brow = ((bn < nsplitB) ? (B0 + (size_t)bn * K)
                                      : (B1 + (size_t)(bn - nsplitB) * K)) + lk;

  const int tx = tid & 15, ty = tid >> 4;
  float acc[2][2][4][4] = {};

  float4 pa0 = *(const float4*)(arow);
  float4 pa1 = *(const float4*)(arow + 4);
  float4 pb0 = *(const float4*)(brow);
  float4 pb1 = *(const float4*)(brow + 4);

  int k0 = 0;
  while (true) {
    __syncthreads();
    As[lk + 0][lrow] = pa0.x; As[lk + 1][lrow] = pa0.y;
    As[lk + 2][lrow] = pa0.z; As[lk + 3][lrow] = pa0.w;
    As[lk + 4][lrow] = pa1.x; As[lk + 5][lrow] = pa1.y;
    As[lk + 6][lrow] = pa1.z; As[lk + 7][lrow] = pa1.w;
    Bs[lk + 0][lrow] = pb0.x; Bs[lk + 1][lrow] = pb0.y;
    Bs[lk + 2][lrow] = pb0.z; Bs[lk + 3][lrow] = pb0.w;
    Bs[lk + 4][lrow] = pb1.x; Bs[lk + 5][lrow] = pb1.y;
    Bs[lk + 6][lrow] = pb1.z; Bs[lk + 7][lrow] = pb1.w;
    __syncthreads();

    k0 += 16;
    const bool more = (k0 < K);
    if (more) {
      pa0 = *(const float4*)(arow + k0);
      pa1 = *(const float4*)(arow + k0 + 4);
      pb0 = *(const float4*)(brow + k0);
      pb1 = *(const float4*)(brow + k0 + 4);
    }

#pragma unroll
    for (int k = 0; k < 16; ++k) {
      const float4 av0 = *(const float4*)&As[k][ty * 4];
      const float4 av1 = *(const float4*)&As[k][64 + ty * 4];
      const float4 bv0 = *(const float4*)&Bs[k][tx * 4];
      const float4 bv1 = *(const float4*)&Bs[k][64 + tx * 4];
      const float am[2][4] = {{av0.x, av0.y, av0.z, av0.w},
                              {av1.x, av1.y, av1.z, av1.w}};
      const float bw[2][4] = {{bv0.x, bv0.y, bv0.z, bv0.w},
                              {bv1.x, bv1.y, bv1.z, bv1.w}};
#pragma unroll
      for (int im = 0; im < 2; ++im)
#pragma unroll
        for (int in = 0; in < 2; ++in)
#pragma unroll
          for (int i = 0; i < 4; ++i)
#pragma unroll
            for (int j = 0; j < 4; ++j)
              acc[im][in][i][j] += am[im][i] * bw[in][j];
    }
    if (!more) break;
  }

  float bb[2][4];
#pragma unroll
  for (int in = 0; in < 2; ++in)
#pragma unroll
    for (int j = 0; j < 4; ++j) bb[in][j] = 0.f;
  if (bias0) {
#pragma unroll
    for (int in = 0; in < 2; ++in)
#pragma unroll
      for (int j = 0; j < 4; ++j) {
        int n = n0 + in * 64 + tx * 4 + j;
        bb[in][j] = (n < nsplitBias) ? bias0[n] : bias1[n - nsplitBias];
      }
  }
#pragma unroll
  for (int im = 0; im < 2; ++im)
#pragma unroll
    for (int i = 0; i < 4; ++i) {
      const int m = m0 + im * 64 + ty * 4 + i;
#pragma unroll
      for (int in = 0; in < 2; ++in) {
        float4 o;
        o.x = acc[im][in][i][0] + bb[in][0];
        o.y = acc[im][in][i][1] + bb[in][1];
        o.z = acc[im][in][i][2] + bb[in][2];
        o.w = acc[im][in][i][3] + bb[in][3];
        *(float4*)&C[(size_t)m * N + n0 + in * 64 + tx * 4] = o;
      }
    }
}

// ---------------------------------------------------------------------------
// BiLSTM recurrence (unchanged).
// ---------------------------------------------------------------------------
__global__ __launch_bounds__(512) void lstm_esplit(
    const float* __restrict__ Xg,
    const float* __restrict__ Whh_f, const float* __restrict__ Whh_b,
    unsigned long long* __restrict__ hxbuf,  // [2 parity][64 chain][256] qwords
    float* __restrict__ blstm)
{
  const int tid = threadIdx.x;
  const int pid = blockIdx.x;
  const int hf = pid >> 6, chain = pid & 63;   // peer WG = pid^64 (same XCD slot)
  const int d = chain >> 5, b = chain & 31;
  const int j = tid & 127;              // element within own half
  const int g = tid >> 7;               // gate 0=i,1=f,2=g,3=o
  const int elem = hf * 128 + j;        // element 0..255
  const int grow = g * 256 + elem;      // global gate row 0..1023

  const float* W = (d ? Whh_b : Whh_f) + (size_t)grow * 256;
  float4 w4[64];
#pragma unroll
  for (int i = 0; i < 64; ++i) w4[i] = *(const float4*)(W + 4 * i);

  __shared__ float h_lds[HIDN];
  __shared__ float gsL[512];
  float creg = 0.f;                     // cell for element `elem` (threads tid<128)
  if (tid < HIDN) h_lds[tid] = 0.f;
  __syncthreads();

  const float4* h4 = (const float4*)h_lds;
  const int peerbase = (1 - hf) * 128;
  const size_t xgoff = (size_t)d * 1024 + grow;

  for (int it = 0; it < SEQB; ++it) {
    const int t = d ? (SEQB - 1 - it) : it;
    const size_t m = (size_t)t * BATCH + b;
    const float xv = Xg[m * 2048 + xgoff];   // overlaps the poll below

    // --- poll peer h-half (tag == it; zero-init covers it=0) ---
    if (tid < 128) {
      const unsigned long long* src =
          &hxbuf[((size_t)(it & 1) * 64 + chain) * 256 + peerbase + tid];
      unsigned long long q;
      do { q = __hip_atomic_load(src, __ATOMIC_RELAXED, SCOPE_AGENT); }
      while ((unsigned)(q >> 32) != (unsigned)it);
      h_lds[peerbase + tid] = __uint_as_float((unsigned)q);
    }
    __syncthreads();

    // --- full MAC, straight-line, constant w4 indices ---
    float a0 = 0.f, a1 = 0.f, a2 = 0.f, a3 = 0.f;
#pragma unroll
    for (int i = 0; i < 64; ++i) {
      const float4 hv = h4[i];               // wave-uniform -> LDS broadcast
      const float4 wv = w4[i];
      a0 += wv.x * hv.x; a1 += wv.y * hv.y; a2 += wv.z * hv.z; a3 += wv.w * hv.w;
    }
    gsL[tid] = (a0 + a1) + (a2 + a3) + xv;   // gate g of element elem at [g*128+j]
    __syncthreads();

    // --- cell update for own 128 elements (all gates LOCAL) ---
    if (tid < 128) {
      const float gi = gsL[tid], gf = gsL[128 + tid];
      const float gg = gsL[256 + tid], go = gsL[384 + tid];
      creg = sigm(gf) * creg + sigm(gi) * tanh_f(gg);
      const float hn = sigm(go) * tanh_f(creg);
      h_lds[elem] = hn;
      const unsigned long long pk =
          ((unsigned long long)(unsigned)(it + 1) << 32) |
          (unsigned long long)__float_as_uint(hn);
      __hip_atomic_store(&hxbuf[((size_t)((it + 1) & 1) * 64 + chain) * 256 + elem], pk,
                         __ATOMIC_RELAXED, SCOPE_AGENT);
      blstm[m * HH2 + (size_t)d * HIDN + elem] = hn;
    }
    __syncthreads();
  }
}

// ---------------------------------------------------------------------------
__global__ __launch_bounds__(256) void attn_k(const float* __restrict__ blstm,
                                              const float* __restrict__ attn_w,
                                              const float* __restrict__ attn_b,
                                              float* __restrict__ attnv)
{
  const int tid = threadIdx.x;
  const int p = blockIdx.x * 4 + (tid >> 6);
  const int lane = tid & 63;
  const size_t base = (size_t)p * HH2 + lane * 8;
  float4 v0 = *(const float4*)&blstm[base];
  float4 v1 = *(const float4*)&blstm[base + 4];
  float4 w0 = *(const float4*)&attn_w[lane * 8];
  float4 w1 = *(const float4*)&attn_w[lane * 8 + 4];
  float acc = v0.x * w0.x + v0.y * w0.y + v0.z * w0.z + v0.w * w0.w
            + v1.x * w1.x + v1.y * w1.y + v1.z * w1.z + v1.w * w1.w;
#pragma unroll
  for (int off = 32; off > 0; off >>= 1) acc += __shfl_down(acc, off);
  if (lane == 0) attnv[p] = acc + attn_b[0];
}

// ---------------------------------------------------------------------------
__global__ __launch_bounds__(64) void entity_prep(const int* __restrict__ spans,
                                                  const float* __restrict__ attnv,
                                                  const float* __restrict__ blstm,
                                                  float* __restrict__ Hent,
                                                  float* __restrict__ P_out)
{
  const int nb = blockIdx.x;
  const int n = nb >> 5, b = nb & 31;
  const int tid = threadIdx.x;
  __shared__ float sc[8];
  if (tid < 8) sc[tid] = attnv[spans[n * 8 + tid] * BATCH + b];
  __syncthreads();
  float mx = sc[0];
#pragma unroll
  for (int w = 1; w < 8; ++w) mx = fmaxf(mx, sc[w]);
  float ex[8]; float ssum = 0.f;
#pragma unroll
  for (int w = 0; w < 8; ++w) { ex[w] = __expf(sc[w] - mx); ssum += ex[w]; }
  float wsum = 0.f;
#pragma unroll
  for (int w = 0; w < 8; ++w) wsum += ex[w] / ssum;
  const size_t base = ((size_t)n * BATCH + b) * HH2;
#pragma unroll
  for (int q = 0; q < 2; ++q) {
    int j = q * 256 + tid * 4;
    float4 v = *(const float4*)&blstm[base + j];
    v.x *= wsum; v.y *= wsum; v.z *= wsum; v.w *= wsum;
    *(float4*)&Hent[base + j] = v;
  }
  if (tid == 0) {
    P_out[((size_t)b * NNODE + n) * 2 + 0] = 0.001f;
    P_out[((size_t)b * NNODE + n) * 2 + 1] = 0.999f;
  }
}

// ---------------------------------------------------------------------------
__global__ void pack_ucat(const float* __restrict__ U_ioc, const float* __restrict__ Uf,
                          float* __restrict__ Ucat)
{
  int j = blockIdx.x, tid = threadIdx.x;
  for (int k = tid; k < 512; k += 128) {
    float v;
    if (j < 1536)      v = U_ioc[(size_t)j * 1024 + k];
    else if (j < 3072) v = U_ioc[(size_t)(j - 1536) * 1024 + 512 + k];
    else               v = Uf[(size_t)(j - 3072) * 512 + k];
    Ucat[(size_t)j * 512 + k] = v;
  }
}

// ---------------------------------------------------------------------------
__global__ __launch_bounds__(256) void elem_pre(const float* __restrict__ W_ioc,
                                                const float* __restrict__ b_ioc,
                                                const float* __restrict__ Wf,
                                                const float* __restrict__ bf,
                                                const float* __restrict__ elem_emb,
                                                float* __restrict__ WiocE,
                                                float* __restrict__ WfE)
{
  const int el = blockIdx.x, tid = threadIdx.x;
  __shared__ float ee[RDIM];
  if (tid < RDIM) ee[tid] = elem_emb[el * RDIM + tid];
  __syncthreads();
  for (int r = tid; r < 1536; r += 256) {
    float acc = b_ioc[r];
#pragma unroll 8
    for (int k = 0; k < RDIM; ++k) acc += W_ioc[(size_t)r * RDIM + k] * ee[k];
    WiocE[(size_t)el * 1536 + r] = acc;
  }
  for (int r = tid; r < 512; r += 256) {
    float acc = bf[r];
#pragma unroll 8
    for (int k = 0; k < RDIM; ++k) acc += Wf[(size_t)r * RDIM + k] * ee[k];
    WfE[(size_t)el * 512 + r] = acc;
  }
}

// ---------------------------------------------------------------------------
__global__ __launch_bounds__(256) void mprep(const float* __restrict__ W1,
                                             const float* __restrict__ b1,
                                             const float* __restrict__ W2,
                                             const float* __restrict__ b2,
                                             float* __restrict__ Mmat,
                                             float* __restrict__ mbv)
{
  const int tid = threadIdx.x;
  for (int j = tid; j < 512; j += 256) {
    float a0 = 0.f, a1 = 0.f;
    for (int m = 0; m < 1024; ++m) {
      float w = W1[(size_t)m * 512 + j];
      a0 += W2[m] * w;
      a1 += W2[1024 + m] * w;
    }
    Mmat[j] = a0; Mmat[512 + j] = a1;
  }
  if (tid < 2) {
    float a = b2[tid];
    for (int m = 0; m < 1024; ++m) a += W2[tid * 1024 + m] * b1[m];
    mbv[tid] = a;
  }
}

// ---------------------------------------------------------------------------
// DAG-LSTM sequential kernel. Master changes vs R9:
//  (a) background confirmation: wave-7 lanes probe `arrive` for published-but-
//      unconfirmed relation nodes (pipelined across steps so LLC latency never
//      touches the barrier path); tid0 merges into confL under the existing
//      barriers. First consumptions then take the fast prefetch path instead
//      of the slow wait+sync-reload path. Wait path kept verbatim as fallback.
//  (b) publish-path barrier merge: hh stored to hbuf speculatively before the
//      reduce barrier (its vmcnt(0) drain is the store fence), head published
//      by tid0 inside its existing serial section. Removes 2 barriers/publish.
// ---------------------------------------------------------------------------
__global__ __launch_bounds__(512) void dag_seq(
    const int* __restrict__ S, const int* __restrict__ T, const int* __restrict__ EN,
    const int* __restrict__ entsz,
    const float* __restrict__ WiocE, const float* __restrict__ WfE,
    const float* __restrict__ Mmat, const float* __restrict__ mbv,
    float* __restrict__ Tall, float* __restrict__ hbuf,
    uint32_t* head, uint32_t* slotbase, uint32_t* arrive,
    const float* __restrict__ Ucat, float* __restrict__ P_out)
{
  const int tid = threadIdx.x;
  __shared__ int   SL[NSt * BATCH * 2];
  __shared__ int   TLt[NSt * BATCH];
  __shared__ int   ELt[NSt * BATCH];
  __shared__ int   eszL[BATCH];
  __shared__ float MmatL[1024];
  __shared__ float mbvL[2];
  __shared__ float pstL[NNODE];
  __shared__ int   evtofL[NSt];
  __shared__ int   confL[NSt];
  __shared__ int   confN[32];
  __shared__ int   anyflag;
  __shared__ float red0[8], red1[8], bcast[2];
  __shared__ uint32_t sslot;

  if (blockIdx.x < NHELP) {
    const int w = blockIdx.x;
    const int row = w * 32 + (tid >> 4);
    const int ks = (tid & 15) * 32;
    float wreg[32];
#pragma unroll
    for (int i = 0; i < 8; ++i) {
      float4 v = *(const float4*)&Ucat[(size_t)row * 512 + ks + i * 4];
      wreg[i * 4 + 0] = v.x; wreg[i * 4 + 1] = v.y; wreg[i * 4 + 2] = v.z; wreg[i * 4 + 3] = v.w;
    }
    uint32_t done = 0;
    const int g = w & 7;
    while (true) {
      if (tid == 0) {
        while (__hip_atomic_load(head, __ATOMIC_RELAXED, SCOPE_AGENT) <= done) {
          __builtin_amdgcn_s_sleep(4);
        }
        __builtin_amdgcn_fence(__ATOMIC_ACQUIRE, "agent");
        sslot = slotbase[done];
      }
      __syncthreads();
      const uint32_t slot = sslot;
      if (slot == TERMEVT) break;
      const float* hv = hbuf + (size_t)done * HH2 + ks;
      float acc = 0.f;
#pragma unroll
      for (int i = 0; i < 8; ++i) {
        float4 v = *(const float4*)&hv[i * 4];
        acc += wreg[i * 4 + 0] * v.x + wreg[i * 4 + 1] * v.y
             + wreg[i * 4 + 2] * v.z + wreg[i * 4 + 3] * v.w;
      }
      acc += __shfl_down(acc, 8);
      acc += __shfl_down(acc, 4);
      acc += __shfl_down(acc, 2);
      acc += __shfl_down(acc, 1);
      if ((tid & 15) == 0) {
        __hip_atomic_store(&Tall[(size_t)slot + row], acc, __ATOMIC_RELAXED, SCOPE_AGENT);
      }
      __syncthreads();
      if (tid == 0) {
        __hip_atomic_fetch_add(&arrive[done * 8 + g], 1u, __ATOMIC_RELEASE, SCOPE_AGENT);
      }
      ++done;
    }
    return;
  }

  // master
  for (int i = tid; i < NSt * BATCH * 2; i += 512) SL[i] = S[i];
  for (int i = tid; i < NSt * BATCH; i += 512) { TLt[i] = T[i]; ELt[i] = EN[i]; }
  for (int i = tid; i < 1024; i += 512) MmatL[i] = Mmat[i];
  if (tid < BATCH) eszL[tid] = entsz[tid];
  if (tid < 2) mbvL[tid] = mbv[tid];
  __syncthreads();

  float c = 0.f;
  uint32_t e = 0;
  for (int b = 0; b < BATCH; ++b) {
    const int esz = eszL[b];
    for (int j = tid; j < NNODE; j += 512) pstL[j] = (j < NEnt) ? 0.999f : 0.f;
    if (tid < NSt) { confL[tid] = 0; evtofL[tid] = -1; }
    if (tid < 32) confN[tid] = 0;
    if (tid == 0) anyflag = 0;
    __syncthreads();

    bool  pfok = false;
    float pt0 = 0.f, pt1 = 0.f, pt2 = 0.f, pt3 = 0.f, pt4 = 0.f, pt5 = 0.f, pt6 = 0.f, pt7 = 0.f;
    float pw0 = 0.f, pw1 = 0.f, pw2 = 0.f, pwf = 0.f;

    // background-probe pipeline state (wave-7 lanes 448..479 own node r=tid-448)
    uint32_t pr0 = 0, pr1 = 0, pr2 = 0, pr3 = 0, pr4 = 0, pr5 = 0, pr6 = 0, pr7 = 0;
    int prvalid = 0, prdone = 0;
    int lastseen = 0;   // tid0's view of anyflag

#define PFETCH(sn)                                                              \
    do {                                                                        \
      pfok = false;                                                             \
      if ((sn) < NSt) {                                                         \
        const int sbn_ = (sn) * BATCH + b;                                      \
        const int na0_ = SL[2 * sbn_], na1_ = SL[2 * sbn_ + 1];                 \
        const int nel_ = ELt[sbn_];                                             \
        if (nel_ >= 0) {                                                        \
          const float* nwe_ = WiocE + (size_t)nel_ * 1536;                      \
          const float* nwf_ = WfE + (size_t)nel_ * 512;                         \
          pw0 = nwe_[tid]; pw1 = nwe_[512 + tid]; pw2 = nwe_[1024 + tid];       \
          pwf = nwf_[tid];                                                      \
        }                                                                       \
        const bool ok0_ = (na0_ < NEnt) || (confL[na0_ - NEnt] != 0);           \
        const bool ok1_ = (na1_ < NEnt) || (confL[na1_ - NEnt] != 0);           \
        if (ok0_ && ok1_) {                                                     \
          const size_t ns0_ = ((size_t)na0_ * BATCH + b) * NROWS;               \
          const size_t ns1_ = ((size_t)na1_ * BATCH + b) * NROWS;               \
          pt0 = Tall[ns0_ + tid];               pt1 = Tall[ns1_ + 1536 + tid];  \
          pt2 = Tall[ns0_ + 512 + tid];         pt3 = Tall[ns1_ + 2048 + tid];  \
          pt4 = Tall[ns0_ + 1024 + tid];        pt5 = Tall[ns1_ + 2560 + tid];  \
          pt6 = Tall[ns0_ + 3072 + tid];        pt7 = Tall[ns1_ + 3072 + tid];  \
          pfok = true;                                                          \
        }                                                                       \
      }                                                                         \
    } while (0)

    // Pipelined background probe: consume last step's arrive loads, then
    // issue this step's. LLC latency spans a whole step, never a barrier.
#define PROBE()                                                                 \
    do {                                                                        \
      if (tid >= 448 && tid < 480) {                                            \
        const int r_ = tid - 448;                                               \
        if (prvalid) {                                                          \
          prvalid = 0;                                                          \
          if (pr0 >= (uint32_t)HPG && pr1 >= (uint32_t)HPG &&                   \
              pr2 >= (uint32_t)HPG && pr3 >= (uint32_t)HPG &&                   \
              pr4 >= (uint32_t)HPG && pr5 >= (uint32_t)HPG &&                   \
              pr6 >= (uint32_t)HPG && pr7 >= (uint32_t)HPG) {                   \
            confN[r_] = 1;                                                      \
            atomicAdd(&anyflag, 1);                                             \
            prdone = 1;                                                         \
          }                                                                     \
        }                                                                       \
        if (!prdone && confL[r_] == 0) {                                        \
          const int ev_ = evtofL[r_];                                           \
          if (ev_ >= 0) {                                                       \
            const uint32_t* ap_ = &arrive[(uint32_t)ev_ * 8];                   \
            pr0 = __hip_atomic_load(ap_ + 0, __ATOMIC_RELAXED, SCOPE_AGENT);    \
            pr1 = __hip_atomic_load(ap_ + 1, __ATOMIC_RELAXED, SCOPE_AGENT);    \
            pr2 = __hip_atomic_load(ap_ + 2, __ATOMIC_RELAXED, SCOPE_AGENT);    \
            pr3 = __hip_atomic_load(ap_ + 3, __ATOMIC_RELAXED, SCOPE_AGENT);    \
            pr4 = __hip_atomic_load(ap_ + 4, __ATOMIC_RELAXED, SCOPE_AGENT);    \
            pr5 = __hip_atomic_load(ap_ + 5, __ATOMIC_RELAXED, SCOPE_AGENT);    \
            pr6 = __hip_atomic_load(ap_ + 6, __ATOMIC_RELAXED, SCOPE_AGENT);    \
            pr7 = __hip_atomic_load(ap_ + 7, __ATOMIC_RELAXED, SCOPE_AGENT);    \
            prvalid = 1;                                                        \
          }                                                                     \
        }                                                                       \
      }                                                                         \
    } while (0)

    // tid0-only: merge background confirmations into confL (acquire fence
    // BEFORE publishing confL so later Tall loads see helper stores).
#define MERGE()                                                                 \
    do {                                                                        \
      if (anyflag != lastseen) {                                                \
        lastseen = anyflag;                                                     \
        __builtin_amdgcn_fence(__ATOMIC_ACQUIRE, "agent");                      \
        for (int r_ = 0; r_ < 32; ++r_)                                         \
          if (confN[r_]) confL[r_] = 1;                                         \
      }                                                                         \
    } while (0)

    PFETCH(0);

    for (int s = 0; s < NSt; ++s) {
      const int sb = s * BATCH + b;
      const int a0 = SL[2 * sb], a1 = SL[2 * sb + 1];
      const int tgt = TLt[sb], el = ELt[sb];
      const bool valid = (tgt >= esz) && (el > -1);
      const float pa0 = pstL[a0], pa1 = pstL[a1];
      const bool cond = valid && (pa0 > 0.5f) && (pa1 > 0.5f);
      if (cond) {
        if (!pfok) {
          const int r0 = (a0 >= NEnt) ? (a0 - NEnt) : -1;
          const int r1 = (a1 >= NEnt) ? (a1 - NEnt) : -1;
          if (tid < 8 && r0 >= 0 && !confL[r0]) {
            const uint32_t ev = (uint32_t)evtofL[r0];
            while (__hip_atomic_load(&arrive[ev * 8 + tid], __ATOMIC_RELAXED, SCOPE_AGENT)
                   < (uint32_t)HPG) { __builtin_amdgcn_s_sleep(1); }
          }
          if (tid >= 8 && tid < 16 && r1 >= 0 && !confL[r1]) {
            const uint32_t ev = (uint32_t)evtofL[r1];
            while (__hip_atomic_load(&arrive[ev * 8 + (tid - 8)], __ATOMIC_RELAXED, SCOPE_AGENT)
                   < (uint32_t)HPG) { __builtin_amdgcn_s_sleep(1); }
          }
          __syncthreads();
          if (tid == 0) {
            __builtin_amdgcn_fence(__ATOMIC_ACQUIRE, "agent");
            if (r0 >= 0) confL[r0] = 1;
            if (r1 >= 0) confL[r1] = 1;
          }
          __syncthreads();
          const size_t s0 = ((size_t)a0 * BATCH + b) * NROWS;
          const size_t s1 = ((size_t)a1 * BATCH + b) * NROWS;
          pt0 = Tall[s0 + tid];        pt1 = Tall[s1 + 1536 + tid];
          pt2 = Tall[s0 + 512 + tid];  pt3 = Tall[s1 + 2048 + tid];
          pt4 = Tall[s0 + 1024 + tid]; pt5 = Tall[s1 + 2560 + tid];
          pt6 = Tall[s0 + 3072 + tid]; pt7 = Tall[s1 + 3072 + tid];
        }
        const float ii = pw0 + pt0 + pt1;
        const float oo = pw1 + pt2 + pt3;
        const float ch = pw2 + pt4 + pt5;
        const float f0 = sigm(pwf + pt6);
        const float f1 = sigm(pwf + pt7);
        PFETCH(s + 1);
        PROBE();
        float cn = (f0 + f1) * c + sigm(ii) * tanh_f(ch);
        cn = fminf(fmaxf(cn, -100.f), 100.f);
        float hh = sigm(oo) * tanh_f(cn);
        hh = fminf(fmaxf(hh, -100.f), 100.f);
        // speculative hbuf store: if this step turns out to publish, the
        // reduce barrier's vmcnt(0) drain orders it before tid0's head release.
        if (tgt < NEnt + 32) {
          __hip_atomic_store(&hbuf[(size_t)e * HH2 + tid], hh, __ATOMIC_RELAXED, SCOPE_AGENT);
        }
        float l0 = MmatL[tid] * hh, l1 = MmatL[512 + tid] * hh;
#pragma unroll
        for (int off = 32; off > 0; off >>= 1) {
          l0 += __shfl_down(l0, off);
          l1 += __shfl_down(l1, off);
        }
        if ((tid & 63) == 0) { red0[tid >> 6] = l0; red1[tid >> 6] = l1; }
        __syncthreads();
        if (tid == 0) {
          MERGE();
          float L0 = mbvL[0], L1 = mbvL[1];
#pragma unroll
          for (int wv = 0; wv < 8; ++wv) { L0 += red0[wv]; L1 += red1[wv]; }
          float mx = fmaxf(L0, L1);
          float e0 = __expf(L0 - mx), e1 = __expf(L1 - mx);
          float inv = 1.f / (e0 + e1);
          const float o0 = e0 * inv, o1 = e1 * inv;
          bcast[0] = o0; bcast[1] = o1;
          pstL[tgt] = o1;
          P_out[((size_t)b * NNODE + tgt) * 2 + 0] = o0;
          P_out[((size_t)b * NNODE + tgt) * 2 + 1] = o1;
          if (o1 > 0.5f && tgt < NEnt + 32) {
            evtofL[tgt - NEnt] = (int)e;
            __hip_atomic_store(&slotbase[e], (uint32_t)(((uint32_t)tgt * BATCH + (uint32_t)b) * NROWS),
                               __ATOMIC_RELAXED, SCOPE_AGENT);
            __hip_atomic_store(head, e + 1u, __ATOMIC_RELEASE, SCOPE_AGENT);
          }
        }
        __syncthreads();
        c = cn;
        if (bcast[1] > 0.5f && tgt < NEnt + 32) ++e;
      } else {
        PFETCH(s + 1);
        PROBE();
        if (tid == 0) {
          MERGE();
          const float o0 = valid ? 0.999f : ((tgt < NEnt) ? 0.001f : 0.f);
          const float o1 = valid ? 0.001f : ((tgt < NEnt) ? 0.999f : 0.f);
          if (valid || tgt >= NEnt) {
            P_out[((size_t)b * NNODE + tgt) * 2 + 0] = o0;
            P_out[((size_t)b * NNODE + tgt) * 2 + 1] = o1;
          }
          if (valid) pstL[tgt] = o1;
        }
        __syncthreads();
      }
    }
#undef PFETCH
#undef PROBE
#undef MERGE
  }
  if (tid == 0) {
    __hip_atomic_store(&slotbase[e], TERMEVT, __ATOMIC_RELAXED, SCOPE_AGENT);
    __hip_atomic_store(head, e + 1u, __ATOMIC_RELEASE, SCOPE_AGENT);
  }
}

// ---------------------------------------------------------------------------
extern "C" void kernel_launch(void* const* d_in, const int* in_sizes, int n_in,
                              void* d_out, int out_size, void* d_ws, size_t ws_size,
                              hipStream_t stream)
{
  const int* tokens = (const int*)d_in[0];
  const int* spans  = (const int*)d_in[1];
  const int* enames = (const int*)d_in[2];
  const int* T      = (const int*)d_in[5];
  const int* S      = (const int*)d_in[6];
  const int* entsz  = (const int*)d_in[7];
  const float* word_emb = (const float*)d_in[8];
  const float* elem_emb = (const float*)d_in[9];
  const float* attn_w = (const float*)d_in[10];
  const float* attn_b = (const float*)d_in[11];
  const float* Wih_f = (const float*)d_in[12];
  const float* Whh_f = (const float*)d_in[13];
  const float* bl_f  = (const float*)d_in[14];
  const float* Wih_b = (const float*)d_in[15];
  const float* Whh_b = (const float*)d_in[16];
  const float* bl_b  = (const float*)d_in[17];
  const float* W_ioc = (const float*)d_in[18];
  const float* U_ioc = (const float*)d_in[19];
  const float* b_ioc = (const float*)d_in[20];
  const float* Wf    = (const float*)d_in[21];
  const float* Uf    = (const float*)d_in[22];
  const float* bf    = (const float*)d_in[23];
  const float* W1    = (const float*)d_in[24];
  const float* b1    = (const float*)d_in[25];
  const float* W2    = (const float*)d_in[26];
  const float* b2    = (const float*)d_in[27];
  float* P_out = (float*)d_out;

  char* ws = (char*)d_ws;
  uint32_t* head     = (uint32_t*)ws;                    // @0
  uint32_t* slotbase = (uint32_t*)(ws + 8192);           // 1024 u32
  uint32_t* arrive   = (uint32_t*)(ws + 16384);          // 8*1024 u32 = 32KB
  float* fws = (float*)(ws + 65536);
  size_t off = 0;
  float* Xg    = fws + off; off += (size_t)16384 * 2048;
  float* blstm = fws + off; off += (size_t)SEQB * BATCH * HH2;
  float* attnv = fws + off; off += (size_t)SEQB * BATCH;
  float* Hent  = fws + off; off += (size_t)2048 * 512;
  float* Tall  = fws + off; off += (size_t)96 * BATCH * NROWS;
  unsigned long long* hxbuf = (unsigned long long*)(fws + off);
  off += (size_t)2 * 64 * 256 * 2;           // qwords = 2 floats each
  float* Ucat  = fws + off; off += (size_t)NROWS * 512;
  float* WiocE = fws + off; off += (size_t)128 * 1536;
  float* WfE   = fws + off; off += (size_t)128 * 512;
  float* Mmat  = fws + off; off += 1024;
  float* mbv   = fws + off; off += 16;
  float* hbuf  = fws + off; off += (size_t)1024 * 512;
  const size_t needed = 65536 + off * sizeof(float);
  if (ws_size < needed) return;   // workspace too small: bail (visible failure)

  hipMemsetAsync(d_ws, 0, 65536, stream);
  // hxbuf must start as tag=0/value=0 (valid "h=0 at step 0" records)
  hipMemsetAsync(hxbuf, 0, (size_t)2 * 64 * 256 * 8, stream);

  // 1) Xg = gather(word_emb, tokens) @ [Wih_f;Wih_b].T + [bl_f;bl_b]
  gemm_tn<1><<<dim3(2048 / 128, 16384 / 128), 256, 0, stream>>>(
      nullptr, tokens, word_emb, Wih_f, Wih_b, 1024, bl_f, bl_b, 1024,
      Xg, 16384, 2048, 256);

  // 2) recurrent BiLSTM (element-split, tagged h exchange, resident weights)
  lstm_esplit<<<128, 512, 0, stream>>>(Xg, Whh_f, Whh_b, hxbuf, blstm);

  // 3) attention scores + entity H
  attn_k<<<4096, 256, 0, stream>>>(blstm, attn_w, attn_b, attnv);
  entity_prep<<<2048, 64, 0, stream>>>(spans, attnv, blstm, Hent, P_out);

  // 4) DAG-LSTM precompute
  pack_ucat<<<NROWS, 128, 0, stream>>>(U_ioc, Uf, Ucat);
  elem_pre<<<128, 256, 0, stream>>>(W_ioc, b_ioc, Wf, bf, elem_emb, WiocE, WfE);
  mprep<<<1, 256, 0, stream>>>(W1, b1, W2, b2, Mmat, mbv);
  gemm_tn<0><<<dim3(NROWS / 128, 2048 / 128), 256, 0, stream>>>(
      Hent, nullptr, nullptr, Ucat, nullptr, 0x40000000, nullptr, nullptr, 0,
      Tall, 2048, NROWS, 512);

  // 5) sequential DAG-LSTM with helper projection grid
  dag_seq<<<NHELP + 1, 512, 0, stream>>>(S, T, enames, entsz, WiocE, WfE, Mmat, mbv,
                                         Tall, hbuf, head, slotbase, arrive, Ucat, P_out);
}

// Round 3
// 6447.394 us; speedup vs baseline: 1.0686x; 1.0686x over previous
//
#include <hip/hip_runtime.h>
#include <stdint.h>

#define SEQB 512
#define BATCH 32
#define EDIM 256
#define HIDN 256
#define HH2 512
#define RDIM 128
#define NEnt 64
#define NSt 64
#define NNODE 128
#define NHELP 112
#define HPG 14          // helpers per arrive-group (112/8)
#define NROWS 3584      // 1536 (U0) + 1536 (U1) + 512 (Uf)
#define TERMEVT 0xFFFFFFFFu
#define SCOPE_AGENT __HIP_MEMORY_SCOPE_AGENT

static __device__ __forceinline__ float sigm(float x) { return 1.0f / (1.0f + __expf(-x)); }
static __device__ __forceinline__ float tanh_f(float x) { return 1.0f - 2.0f / (__expf(2.0f * x) + 1.0f); }

// Barrier that drains ONLY LDS (lgkmcnt), leaving global loads/stores in
// flight across the barrier. __syncthreads() would emit s_waitcnt vmcnt(0)
// lgkmcnt(0) and serialize every prefetch load / output store at LLC latency.
// Use ONLY where no cross-thread data flows through GLOBAL memory.
static __device__ __forceinline__ void barrier_lds() {
  asm volatile("s_waitcnt lgkmcnt(0)" ::: "memory");
  __builtin_amdgcn_sched_barrier(0);
  __builtin_amdgcn_s_barrier();
}

// ---------------------------------------------------------------------------
// Tiled fp32 GEMM: C[m][n] = sum_k Arow(m)[k] * Brow(n)[k] (+ bias[n])
// 128x128 tile, 256 threads, 8x8 per thread (4+4 split), register prefetch.
// BIASFIRST=1 initializes the accumulator with bias (bit-identical to a
// "acc = bias; acc += w*e" scalar chain); BIASFIRST=0 adds bias at the end.
// ---------------------------------------------------------------------------
template<int GATHER, int BIASFIRST>
__global__ __launch_bounds__(256) void gemm_tn(
    const float* __restrict__ A, const int* __restrict__ gidx, const float* __restrict__ gtab,
    const float* __restrict__ B0, const float* __restrict__ B1, int nsplitB,
    const float* __restrict__ bias0, const float* __restrict__ bias1, int nsplitBias,
    float* __restrict__ C, int M, int N, int K)
{
  __shared__ float As[16][132];
  __shared__ float Bs[16][132];
  const int tid = threadIdx.x;
  const int m0 = blockIdx.y * 128, n0 = blockIdx.x * 128;

  const int lrow = tid >> 1;            // 0..127
  const int lk   = (tid & 1) * 8;       // 0 or 8
  const float* arow;
  if (GATHER) arow = gtab + (size_t)gidx[m0 + lrow] * K + lk;
  else        arow = A + (size_t)(m0 + lrow) * K + lk;
  const int bn = n0 + lrow;
  const float* brow = ((bn < nsplitB) ? (B0 + (size_t)bn * K)
                                      : (B1 + (size_t)(bn - nsplitB) * K)) + lk;

  const int tx = tid & 15, ty = tid >> 4;

  float bb[2][4];
#pragma unroll
  for (int in = 0; in < 2; ++in)
#pragma unroll
    for (int j = 0; j < 4; ++j) bb[in][j] = 0.f;
  if (bias0) {
#pragma unroll
    for (int in = 0; in < 2; ++in)
#pragma unroll
      for (int j = 0; j < 4; ++j) {
        int n = n0 + in * 64 + tx * 4 + j;
        bb[in][j] = (n < nsplitBias) ? bias0[n] : bias1[n - nsplitBias];
      }
  }

  float acc[2][2][4][4];
#pragma unroll
  for (int im = 0; im < 2; ++im)
#pragma unroll
    for (int in = 0; in < 2; ++in)
#pragma unroll
      for (int i = 0; i < 4; ++i)
#pragma unroll
        for (int j = 0; j < 4; ++j)
          acc[im][in][i][j] = BIASFIRST ? bb[in][j] : 0.f;

  float4 pa0 = *(const float4*)(arow);
  float4 pa1 = *(const float4*)(arow + 4);
  float4 pb0 = *(const float4*)(brow);
  float4 pb1 = *(const float4*)(brow + 4);

  int k0 = 0;
  while (true) {
    __syncthreads();
    As[lk + 0][lrow] = pa0.x; As[lk + 1][lrow] = pa0.y;
    As[lk + 2][lrow] = pa0.z; As[lk + 3][lrow] = pa0.w;
    As[lk + 4][lrow] = pa1.x; As[lk + 5][lrow] = pa1.y;
    As[lk + 6][lrow] = pa1.z; As[lk + 7][lrow] = pa1.w;
    Bs[lk + 0][lrow] = pb0.x; Bs[lk + 1][lrow] = pb0.y;
    Bs[lk + 2][lrow] = pb0.z; Bs[lk + 3][lrow] = pb0.w;
    Bs[lk + 4][lrow] = pb1.x; Bs[lk + 5][lrow] = pb1.y;
    Bs[lk + 6][lrow] = pb1.z; Bs[lk + 7][lrow] = pb1.w;
    __syncthreads();

    k0 += 16;
    const bool more = (k0 < K);
    if (more) {
      pa0 = *(const float4*)(arow + k0);
      pa1 = *(const float4*)(arow + k0 + 4);
      pb0 = *(const float4*)(brow + k0);
      pb1 = *(const float4*)(brow + k0 + 4);
    }

#pragma unroll
    for (int k = 0; k < 16; ++k) {
      const float4 av0 = *(const float4*)&As[k][ty * 4];
      const float4 av1 = *(const float4*)&As[k][64 + ty * 4];
      const float4 bv0 = *(const float4*)&Bs[k][tx * 4];
      const float4 bv1 = *(const float4*)&Bs[k][64 + tx * 4];
      const float am[2][4] = {{av0.x, av0.y, av0.z, av0.w},
                              {av1.x, av1.y, av1.z, av1.w}};
      const float bw[2][4] = {{bv0.x, bv0.y, bv0.z, bv0.w},
                              {bv1.x, bv1.y, bv1.z, bv1.w}};
#pragma unroll
      for (int im = 0; im < 2; ++im)
#pragma unroll
        for (int in = 0; in < 2; ++in)
#pragma unroll
          for (int i = 0; i < 4; ++i)
#pragma unroll
            for (int j = 0; j < 4; ++j)
              acc[im][in][i][j] += am[im][i] * bw[in][j];
    }
    if (!more) break;
  }

#pragma unroll
  for (int im = 0; im < 2; ++im)
#pragma unroll
    for (int i = 0; i < 4; ++i) {
      const int m = m0 + im * 64 + ty * 4 + i;
#pragma unroll
      for (int in = 0; in < 2; ++in) {
        float4 o;
        o.x = acc[im][in][i][0] + (BIASFIRST ? 0.f : bb[in][0]);
        o.y = acc[im][in][i][1] + (BIASFIRST ? 0.f : bb[in][1]);
        o.z = acc[im][in][i][2] + (BIASFIRST ? 0.f : bb[in][2]);
        o.w = acc[im][in][i][3] + (BIASFIRST ? 0.f : bb[in][3]);
        *(float4*)&C[(size_t)m * N + n0 + in * 64 + tx * 4] = o;
      }
    }
}

// ---------------------------------------------------------------------------
// BiLSTM recurrence (unchanged).
// ---------------------------------------------------------------------------
__global__ __launch_bounds__(512) void lstm_esplit(
    const float* __restrict__ Xg,
    const float* __restrict__ Whh_f, const float* __restrict__ Whh_b,
    unsigned long long* __restrict__ hxbuf,  // [2 parity][64 chain][256] qwords
    float* __restrict__ blstm)
{
  const int tid = threadIdx.x;
  const int pid = blockIdx.x;
  const int hf = pid >> 6, chain = pid & 63;   // peer WG = pid^64 (same XCD slot)
  const int d = chain >> 5, b = chain & 31;
  const int j = tid & 127;              // element within own half
  const int g = tid >> 7;               // gate 0=i,1=f,2=g,3=o
  const int elem = hf * 128 + j;        // element 0..255
  const int grow = g * 256 + elem;      // global gate row 0..1023

  const float* W = (d ? Whh_b : Whh_f) + (size_t)grow * 256;
  float4 w4[64];
#pragma unroll
  for (int i = 0; i < 64; ++i) w4[i] = *(const float4*)(W + 4 * i);

  __shared__ float h_lds[HIDN];
  __shared__ float gsL[512];
  float creg = 0.f;                     // cell for element `elem` (threads tid<128)
  if (tid < HIDN) h_lds[tid] = 0.f;
  __syncthreads();

  const float4* h4 = (const float4*)h_lds;
  const int peerbase = (1 - hf) * 128;
  const size_t xgoff = (size_t)d * 1024 + grow;

  for (int it = 0; it < SEQB; ++it) {
    const int t = d ? (SEQB - 1 - it) : it;
    const size_t m = (size_t)t * BATCH + b;
    const float xv = Xg[m * 2048 + xgoff];   // overlaps the poll below

    // --- poll peer h-half (tag == it; zero-init covers it=0) ---
    if (tid < 128) {
      const unsigned long long* src =
          &hxbuf[((size_t)(it & 1) * 64 + chain) * 256 + peerbase + tid];
      unsigned long long q;
      do { q = __hip_atomic_load(src, __ATOMIC_RELAXED, SCOPE_AGENT); }
      while ((unsigned)(q >> 32) != (unsigned)it);
      h_lds[peerbase + tid] = __uint_as_float((unsigned)q);
    }
    __syncthreads();

    // --- full MAC, straight-line, constant w4 indices ---
    float a0 = 0.f, a1 = 0.f, a2 = 0.f, a3 = 0.f;
#pragma unroll
    for (int i = 0; i < 64; ++i) {
      const float4 hv = h4[i];               // wave-uniform -> LDS broadcast
      const float4 wv = w4[i];
      a0 += wv.x * hv.x; a1 += wv.y * hv.y; a2 += wv.z * hv.z; a3 += wv.w * hv.w;
    }
    gsL[tid] = (a0 + a1) + (a2 + a3) + xv;   // gate g of element elem at [g*128+j]
    __syncthreads();

    // --- cell update for own 128 elements (all gates LOCAL) ---
    if (tid < 128) {
      const float gi = gsL[tid], gf = gsL[128 + tid];
      const float gg = gsL[256 + tid], go = gsL[384 + tid];
      creg = sigm(gf) * creg + sigm(gi) * tanh_f(gg);
      const float hn = sigm(go) * tanh_f(creg);
      h_lds[elem] = hn;
      const unsigned long long pk =
          ((unsigned long long)(unsigned)(it + 1) << 32) |
          (unsigned long long)__float_as_uint(hn);
      __hip_atomic_store(&hxbuf[((size_t)((it + 1) & 1) * 64 + chain) * 256 + elem], pk,
                         __ATOMIC_RELAXED, SCOPE_AGENT);
      blstm[m * HH2 + (size_t)d * HIDN + elem] = hn;
    }
    __syncthreads();
  }
}

// ---------------------------------------------------------------------------
__global__ __launch_bounds__(256) void attn_k(const float* __restrict__ blstm,
                                              const float* __restrict__ attn_w,
                                              const float* __restrict__ attn_b,
                                              float* __restrict__ attnv)
{
  const int tid = threadIdx.x;
  const int p = blockIdx.x * 4 + (tid >> 6);
  const int lane = tid & 63;
  const size_t base = (size_t)p * HH2 + lane * 8;
  float4 v0 = *(const float4*)&blstm[base];
  float4 v1 = *(const float4*)&blstm[base + 4];
  float4 w0 = *(const float4*)&attn_w[lane * 8];
  float4 w1 = *(const float4*)&attn_w[lane * 8 + 4];
  float acc = v0.x * w0.x + v0.y * w0.y + v0.z * w0.z + v0.w * w0.w
            + v1.x * w1.x + v1.y * w1.y + v1.z * w1.z + v1.w * w1.w;
#pragma unroll
  for (int off = 32; off > 0; off >>= 1) acc += __shfl_down(acc, off);
  if (lane == 0) attnv[p] = acc + attn_b[0];
}

// ---------------------------------------------------------------------------
__global__ __launch_bounds__(64) void entity_prep(const int* __restrict__ spans,
                                                  const float* __restrict__ attnv,
                                                  const float* __restrict__ blstm,
                                                  float* __restrict__ Hent,
                                                  float* __restrict__ P_out)
{
  const int nb = blockIdx.x;
  const int n = nb >> 5, b = nb & 31;
  const int tid = threadIdx.x;
  __shared__ float sc[8];
  if (tid < 8) sc[tid] = attnv[spans[n * 8 + tid] * BATCH + b];
  __syncthreads();
  float mx = sc[0];
#pragma unroll
  for (int w = 1; w < 8; ++w) mx = fmaxf(mx, sc[w]);
  float ex[8]; float ssum = 0.f;
#pragma unroll
  for (int w = 0; w < 8; ++w) { ex[w] = __expf(sc[w] - mx); ssum += ex[w]; }
  float wsum = 0.f;
#pragma unroll
  for (int w = 0; w < 8; ++w) wsum += ex[w] / ssum;
  const size_t base = ((size_t)n * BATCH + b) * HH2;
#pragma unroll
  for (int q = 0; q < 2; ++q) {
    int j = q * 256 + tid * 4;
    float4 v = *(const float4*)&blstm[base + j];
    v.x *= wsum; v.y *= wsum; v.z *= wsum; v.w *= wsum;
    *(float4*)&Hent[base + j] = v;
  }
  if (tid == 0) {
    P_out[((size_t)b * NNODE + n) * 2 + 0] = 0.001f;
    P_out[((size_t)b * NNODE + n) * 2 + 1] = 0.999f;
  }
}

// ---------------------------------------------------------------------------
__global__ void pack_ucat(const float* __restrict__ U_ioc, const float* __restrict__ Uf,
                          float* __restrict__ Ucat)
{
  int j = blockIdx.x, tid = threadIdx.x;
  for (int k = tid; k < 512; k += 128) {
    float v;
    if (j < 1536)      v = U_ioc[(size_t)j * 1024 + k];
    else if (j < 3072) v = U_ioc[(size_t)(j - 1536) * 1024 + 512 + k];
    else               v = Uf[(size_t)(j - 3072) * 512 + k];
    Ucat[(size_t)j * 512 + k] = v;
  }
}

// ---------------------------------------------------------------------------
__global__ __launch_bounds__(256) void mprep(const float* __restrict__ W1,
                                             const float* __restrict__ b1,
                                             const float* __restrict__ W2,
                                             const float* __restrict__ b2,
                                             float* __restrict__ Mmat,
                                             float* __restrict__ mbv)
{
  const int tid = threadIdx.x;
  for (int j = tid; j < 512; j += 256) {
    float a0 = 0.f, a1 = 0.f;
    for (int m = 0; m < 1024; ++m) {
      float w = W1[(size_t)m * 512 + j];
      a0 += W2[m] * w;
      a1 += W2[1024 + m] * w;
    }
    Mmat[j] = a0; Mmat[512 + j] = a1;
  }
  if (tid < 2) {
    float a = b2[tid];
    for (int m = 0; m < 1024; ++m) a += W2[tid * 1024 + m] * b1[m];
    mbv[tid] = a;
  }
}

// ---------------------------------------------------------------------------
// DAG-LSTM sequential kernel — R9 structure. Only change: fast-path and
// else-path __syncthreads -> barrier_lds() (LDS-only drain), so the 12
// PFETCH prefetch loads and tid0's P_out stores stay in flight across
// barriers instead of being drained at LLC latency every step. Slow path
// and pub path keep full __syncthreads (correctness: cross-wave global
// visibility before head release / after helper waits).
// WE layout: row el = [1536 ioc | 512 f], stride 2048.
// ---------------------------------------------------------------------------
__global__ __launch_bounds__(512) void dag_seq(
    const int* __restrict__ S, const int* __restrict__ T, const int* __restrict__ EN,
    const int* __restrict__ entsz,
    const float* __restrict__ WE,
    const float* __restrict__ Mmat, const float* __restrict__ mbv,
    float* __restrict__ Tall, float* __restrict__ hbuf,
    uint32_t* head, uint32_t* slotbase, uint32_t* arrive,
    const float* __restrict__ Ucat, float* __restrict__ P_out)
{
  const int tid = threadIdx.x;
  __shared__ int   SL[NSt * BATCH * 2];
  __shared__ int   TLt[NSt * BATCH];
  __shared__ int   ELt[NSt * BATCH];
  __shared__ int   eszL[BATCH];
  __shared__ float MmatL[1024];
  __shared__ float mbvL[2];
  __shared__ float pstL[NNODE];
  __shared__ int   evtofL[NSt];
  __shared__ int   confL[NSt];
  __shared__ float red0[8], red1[8], bcast[2];
  __shared__ uint32_t sslot;

  if (blockIdx.x < NHELP) {
    const int w = blockIdx.x;
    const int row = w * 32 + (tid >> 4);
    const int ks = (tid & 15) * 32;
    float wreg[32];
#pragma unroll
    for (int i = 0; i < 8; ++i) {
      float4 v = *(const float4*)&Ucat[(size_t)row * 512 + ks + i * 4];
      wreg[i * 4 + 0] = v.x; wreg[i * 4 + 1] = v.y; wreg[i * 4 + 2] = v.z; wreg[i * 4 + 3] = v.w;
    }
    uint32_t done = 0;
    const int g = w & 7;
    while (true) {
      if (tid == 0) {
        while (__hip_atomic_load(head, __ATOMIC_RELAXED, SCOPE_AGENT) <= done) {
          __builtin_amdgcn_s_sleep(4);
        }
        __builtin_amdgcn_fence(__ATOMIC_ACQUIRE, "agent");
        sslot = slotbase[done];
      }
      __syncthreads();
      const uint32_t slot = sslot;
      if (slot == TERMEVT) break;
      const float* hv = hbuf + (size_t)done * HH2 + ks;
      float acc = 0.f;
#pragma unroll
      for (int i = 0; i < 8; ++i) {
        float4 v = *(const float4*)&hv[i * 4];
        acc += wreg[i * 4 + 0] * v.x + wreg[i * 4 + 1] * v.y
             + wreg[i * 4 + 2] * v.z + wreg[i * 4 + 3] * v.w;
      }
      acc += __shfl_down(acc, 8);
      acc += __shfl_down(acc, 4);
      acc += __shfl_down(acc, 2);
      acc += __shfl_down(acc, 1);
      if ((tid & 15) == 0) {
        __hip_atomic_store(&Tall[(size_t)slot + row], acc, __ATOMIC_RELAXED, SCOPE_AGENT);
      }
      __syncthreads();
      if (tid == 0) {
        __hip_atomic_fetch_add(&arrive[done * 8 + g], 1u, __ATOMIC_RELEASE, SCOPE_AGENT);
      }
      ++done;
    }
    return;
  }

  // master
  for (int i = tid; i < NSt * BATCH * 2; i += 512) SL[i] = S[i];
  for (int i = tid; i < NSt * BATCH; i += 512) { TLt[i] = T[i]; ELt[i] = EN[i]; }
  for (int i = tid; i < 1024; i += 512) MmatL[i] = Mmat[i];
  if (tid < BATCH) eszL[tid] = entsz[tid];
  if (tid < 2) mbvL[tid] = mbv[tid];
  __syncthreads();

  float c = 0.f;
  uint32_t e = 0;
  for (int b = 0; b < BATCH; ++b) {
    const int esz = eszL[b];
    for (int j = tid; j < NNODE; j += 512) pstL[j] = (j < NEnt) ? 0.999f : 0.f;
    if (tid < NSt) confL[tid] = 0;
    __syncthreads();

    bool  pfok = false;
    float pt0 = 0.f, pt1 = 0.f, pt2 = 0.f, pt3 = 0.f, pt4 = 0.f, pt5 = 0.f, pt6 = 0.f, pt7 = 0.f;
    float pw0 = 0.f, pw1 = 0.f, pw2 = 0.f, pwf = 0.f;

#define PFETCH(sn)                                                              \
    do {                                                                        \
      pfok = false;                                                             \
      if ((sn) < NSt) {                                                         \
        const int sbn_ = (sn) * BATCH + b;                                      \
        const int na0_ = SL[2 * sbn_], na1_ = SL[2 * sbn_ + 1];                 \
        const int nel_ = ELt[sbn_];                                             \
        if (nel_ >= 0) {                                                        \
          const float* nwe_ = WE + (size_t)nel_ * 2048;                         \
          pw0 = nwe_[tid]; pw1 = nwe_[512 + tid]; pw2 = nwe_[1024 + tid];       \
          pwf = nwe_[1536 + tid];                                               \
        }                                                                       \
        const bool ok0_ = (na0_ < NEnt) || (confL[na0_ - NEnt] != 0);           \
        const bool ok1_ = (na1_ < NEnt) || (confL[na1_ - NEnt] != 0);           \
        if (ok0_ && ok1_) {                                                     \
          const size_t ns0_ = ((size_t)na0_ * BATCH + b) * NROWS;               \
          const size_t ns1_ = ((size_t)na1_ * BATCH + b) * NROWS;               \
          pt0 = Tall[ns0_ + tid];               pt1 = Tall[ns1_ + 1536 + tid];  \
          pt2 = Tall[ns0_ + 512 + tid];         pt3 = Tall[ns1_ + 2048 + tid];  \
          pt4 = Tall[ns0_ + 1024 + tid];        pt5 = Tall[ns1_ + 2560 + tid];  \
          pt6 = Tall[ns0_ + 3072 + tid];        pt7 = Tall[ns1_ + 3072 + tid];  \
          pfok = true;                                                          \
        }                                                                       \
      }                                                                         \
    } while (0)

    PFETCH(0);

    for (int s = 0; s < NSt; ++s) {
      const int sb = s * BATCH + b;
      const int a0 = SL[2 * sb], a1 = SL[2 * sb + 1];
      const int tgt = TLt[sb], el = ELt[sb];
      const bool valid = (tgt >= esz) && (el > -1);
      const float pa0 = pstL[a0], pa1 = pstL[a1];
      const bool cond = valid && (pa0 > 0.5f) && (pa1 > 0.5f);
      if (cond) {
        if (!pfok) {
          const int r0 = (a0 >= NEnt) ? (a0 - NEnt) : -1;
          const int r1 = (a1 >= NEnt) ? (a1 - NEnt) : -1;
          if (tid < 8 && r0 >= 0 && !confL[r0]) {
            const uint32_t ev = (uint32_t)evtofL[r0];
            while (__hip_atomic_load(&arrive[ev * 8 + tid], __ATOMIC_RELAXED, SCOPE_AGENT)
                   < (uint32_t)HPG) { __builtin_amdgcn_s_sleep(1); }
          }
          if (tid >= 8 && tid < 16 && r1 >= 0 && !confL[r1]) {
            const uint32_t ev = (uint32_t)evtofL[r1];
            while (__hip_atomic_load(&arrive[ev * 8 + (tid - 8)], __ATOMIC_RELAXED, SCOPE_AGENT)
                   < (uint32_t)HPG) { __builtin_amdgcn_s_sleep(1); }
          }
          __syncthreads();
          if (tid == 0) {
            __builtin_amdgcn_fence(__ATOMIC_ACQUIRE, "agent");
            if (r0 >= 0) confL[r0] = 1;
            if (r1 >= 0) confL[r1] = 1;
          }
          __syncthreads();
          const size_t s0 = ((size_t)a0 * BATCH + b) * NROWS;
          const size_t s1 = ((size_t)a1 * BATCH + b) * NROWS;
          pt0 = Tall[s0 + tid];        pt1 = Tall[s1 + 1536 + tid];
          pt2 = Tall[s0 + 512 + tid];  pt3 = Tall[s1 + 2048 + tid];
          pt4 = Tall[s0 + 1024 + tid]; pt5 = Tall[s1 + 2560 + tid];
          pt6 = Tall[s0 + 3072 + tid]; pt7 = Tall[s1 + 3072 + tid];
        }
        const float ii = pw0 + pt0 + pt1;
        const float oo = pw1 + pt2 + pt3;
        const float ch = pw2 + pt4 + pt5;
        const float f0 = sigm(pwf + pt6);
        const float f1 = sigm(pwf + pt7);
        PFETCH(s + 1);
        float cn = (f0 + f1) * c + sigm(ii) * tanh_f(ch);
        cn = fminf(fmaxf(cn, -100.f), 100.f);
        float hh = sigm(oo) * tanh_f(cn);
        hh = fminf(fmaxf(hh, -100.f), 100.f);
        float l0 = MmatL[tid] * hh, l1 = MmatL[512 + tid] * hh;
#pragma unroll
        for (int off = 32; off > 0; off >>= 1) {
          l0 += __shfl_down(l0, off);
          l1 += __shfl_down(l1, off);
        }
        if ((tid & 63) == 0) { red0[tid >> 6] = l0; red1[tid >> 6] = l1; }
        barrier_lds();
        if (tid == 0) {
          float L0 = mbvL[0], L1 = mbvL[1];
#pragma unroll
          for (int wv = 0; wv < 8; ++wv) { L0 += red0[wv]; L1 += red1[wv]; }
          float mx = fmaxf(L0, L1);
          float e0 = __expf(L0 - mx), e1 = __expf(L1 - mx);
          float inv = 1.f / (e0 + e1);
          const float o0 = e0 * inv, o1 = e1 * inv;
          bcast[0] = o0; bcast[1] = o1;
          pstL[tgt] = o1;
          P_out[((size_t)b * NNODE + tgt) * 2 + 0] = o0;
          P_out[((size_t)b * NNODE + tgt) * 2 + 1] = o1;
        }
        barrier_lds();
        c = cn;
        const bool pub = (bcast[1] > 0.5f) && (tgt < NEnt + 32);
        if (pub) {
          __hip_atomic_store(&hbuf[(size_t)e * HH2 + tid], hh, __ATOMIC_RELAXED, SCOPE_AGENT);
          __syncthreads();   // full drain: hbuf stores from ALL waves must land
          if (tid == 0) {
            evtofL[tgt - NEnt] = (int)e;
            __hip_atomic_store(&slotbase[e], (uint32_t)(((uint32_t)tgt * BATCH + (uint32_t)b) * NROWS),
                               __ATOMIC_RELAXED, SCOPE_AGENT);
            __hip_atomic_store(head, e + 1u, __ATOMIC_RELEASE, SCOPE_AGENT);
          }
          ++e;
          barrier_lds();
        }
      } else {
        PFETCH(s + 1);
        if (tid == 0) {
          const float o0 = valid ? 0.999f : ((tgt < NEnt) ? 0.001f : 0.f);
          const float o1 = valid ? 0.001f : ((tgt < NEnt) ? 0.999f : 0.f);
          if (valid || tgt >= NEnt) {
            P_out[((size_t)b * NNODE + tgt) * 2 + 0] = o0;
            P_out[((size_t)b * NNODE + tgt) * 2 + 1] = o1;
          }
          if (valid) pstL[tgt] = o1;
        }
        barrier_lds();
      }
    }
#undef PFETCH
  }
  if (tid == 0) {
    __hip_atomic_store(&slotbase[e], TERMEVT, __ATOMIC_RELAXED, SCOPE_AGENT);
    __hip_atomic_store(head, e + 1u, __ATOMIC_RELEASE, SCOPE_AGENT);
  }
}

// ---------------------------------------------------------------------------
extern "C" void kernel_launch(void* const* d_in, const int* in_sizes, int n_in,
                              void* d_out, int out_size, void* d_ws, size_t ws_size,
                              hipStream_t stream)
{
  const int* tokens = (const int*)d_in[0];
  const int* spans  = (const int*)d_in[1];
  const int* enames = (const int*)d_in[2];
  const int* T      = (const int*)d_in[5];
  const int* S      = (const int*)d_in[6];
  const int* entsz  = (const int*)d_in[7];
  const float* word_emb = (const float*)d_in[8];
  const float* elem_emb = (const float*)d_in[9];
  const float* attn_w = (const float*)d_in[10];
  const float* attn_b = (const float*)d_in[11];
  const float* Wih_f = (const float*)d_in[12];
  const float* Whh_f = (const float*)d_in[13];
  const float* bl_f  = (const float*)d_in[14];
  const float* Wih_b = (const float*)d_in[15];
  const float* Whh_b = (const float*)d_in[16];
  const float* bl_b  = (const float*)d_in[17];
  const float* W_ioc = (const float*)d_in[18];
  const float* U_ioc = (const float*)d_in[19];
  const float* b_ioc = (const float*)d_in[20];
  const float* Wf    = (const float*)d_in[21];
  const float* Uf    = (const float*)d_in[22];
  const float* bf    = (const float*)d_in[23];
  const float* W1    = (const float*)d_in[24];
  const float* b1    = (const float*)d_in[25];
  const float* W2    = (const float*)d_in[26];
  const float* b2    = (const float*)d_in[27];
  float* P_out = (float*)d_out;

  char* ws = (char*)d_ws;
  uint32_t* head     = (uint32_t*)ws;                    // @0
  uint32_t* slotbase = (uint32_t*)(ws + 8192);           // 1024 u32
  uint32_t* arrive   = (uint32_t*)(ws + 16384);          // 8*1024 u32 = 32KB
  float* fws = (float*)(ws + 65536);
  size_t off = 0;
  float* Xg    = fws + off; off += (size_t)16384 * 2048;
  float* blstm = fws + off; off += (size_t)SEQB * BATCH * HH2;
  float* attnv = fws + off; off += (size_t)SEQB * BATCH;
  float* Hent  = fws + off; off += (size_t)2048 * 512;
  float* Tall  = fws + off; off += (size_t)96 * BATCH * NROWS;
  unsigned long long* hxbuf = (unsigned long long*)(fws + off);
  off += (size_t)2 * 64 * 256 * 2;           // qwords = 2 floats each
  float* Ucat  = fws + off; off += (size_t)NROWS * 512;
  float* WE    = fws + off; off += (size_t)128 * 2048;   // [el][1536 ioc | 512 f]
  float* Mmat  = fws + off; off += 1024;
  float* mbv   = fws + off; off += 16;
  float* hbuf  = fws + off; off += (size_t)1024 * 512;
  const size_t needed = 65536 + off * sizeof(float);
  if (ws_size < needed) return;   // workspace too small: bail (visible failure)

  hipMemsetAsync(d_ws, 0, 65536, stream);
  // hxbuf must start as tag=0/value=0 (valid "h=0 at step 0" records)
  hipMemsetAsync(hxbuf, 0, (size_t)2 * 64 * 256 * 8, stream);

  // 1) Xg = gather(word_emb, tokens) @ [Wih_f;Wih_b].T + [bl_f;bl_b]
  gemm_tn<1, 0><<<dim3(2048 / 128, 16384 / 128), 256, 0, stream>>>(
      nullptr, tokens, word_emb, Wih_f, Wih_b, 1024, bl_f, bl_b, 1024,
      Xg, 16384, 2048, 256);

  // 2) recurrent BiLSTM (element-split, tagged h exchange, resident weights)
  lstm_esplit<<<128, 512, 0, stream>>>(Xg, Whh_f, Whh_b, hxbuf, blstm);

  // 3) attention scores + entity H
  attn_k<<<4096, 256, 0, stream>>>(blstm, attn_w, attn_b, attnv);
  entity_prep<<<2048, 64, 0, stream>>>(spans, attnv, blstm, Hent, P_out);

  // 4) DAG-LSTM precompute
  pack_ucat<<<NROWS, 128, 0, stream>>>(U_ioc, Uf, Ucat);
  // WE[el] = [b_ioc + elem_emb[el] @ W_ioc.T | bf + elem_emb[el] @ Wf.T]
  // (BIASFIRST=1: bias-init + ascending-k FMA chain, bit-identical to the
  //  old elem_pre scalar loop, but with coalesced tiled loads)
  gemm_tn<0, 1><<<dim3(2048 / 128, 1), 256, 0, stream>>>(
      elem_emb, nullptr, nullptr, W_ioc, Wf, 1536, b_ioc, bf, 1536,
      WE, 128, 2048, 128);
  mprep<<<1, 256, 0, stream>>>(W1, b1, W2, b2, Mmat, mbv);
  gemm_tn<0, 0><<<dim3(NROWS / 128, 2048 / 128), 256, 0, stream>>>(
      Hent, nullptr, nullptr, Ucat, nullptr, 0x40000000, nullptr, nullptr, 0,
      Tall, 2048, NROWS, 512);

  // 5) sequential DAG-LSTM with helper projection grid
  dag_seq<<<NHELP + 1, 512, 0, stream>>>(S, T, enames, entsz, WE, Mmat, mbv,
                                         Tall, hbuf, head, slotbase, arrive, Ucat, P_out);
}

// Round 4
// 5488.969 us; speedup vs baseline: 1.2552x; 1.1746x over previous
//
#include <hip/hip_runtime.h>
#include <stdint.h>

#define SEQB 512
#define BATCH 32
#define EDIM 256
#define HIDN 256
#define HH2 512
#define RDIM 128
#define NEnt 64
#define NSt 64
#define NNODE 128
#define NHELP 112
#define HPG 14          // helpers per arrive-group (112/8)
#define NROWS 3584      // 1536 (U0) + 1536 (U1) + 512 (Uf)
#define TERMEVT 0xFFFFFFFFu
#define SCOPE_AGENT __HIP_MEMORY_SCOPE_AGENT

static __device__ __forceinline__ float sigm(float x) { return 1.0f / (1.0f + __expf(-x)); }
static __device__ __forceinline__ float tanh_f(float x) { return 1.0f - 2.0f / (__expf(2.0f * x) + 1.0f); }

// Barrier that drains ONLY LDS (lgkmcnt), leaving global loads/stores in
// flight across the barrier. __syncthreads() would emit s_waitcnt vmcnt(0)
// lgkmcnt(0) and serialize every prefetch load / output store at LLC latency.
// Use ONLY where no cross-thread data flows through GLOBAL memory.
static __device__ __forceinline__ void barrier_lds() {
  asm volatile("s_waitcnt lgkmcnt(0)" ::: "memory");
  __builtin_amdgcn_sched_barrier(0);
  __builtin_amdgcn_s_barrier();
}

// ---------------------------------------------------------------------------
// Tiled fp32 GEMM: C[m][n] = sum_k Arow(m)[k] * Brow(n)[k] (+ bias[n])
// 128x128 tile, 256 threads, 8x8 per thread (4+4 split), register prefetch.
// BIASFIRST=1 initializes the accumulator with bias (bit-identical to a
// "acc = bias; acc += w*e" scalar chain); BIASFIRST=0 adds bias at the end.
// ---------------------------------------------------------------------------
template<int GATHER, int BIASFIRST>
__global__ __launch_bounds__(256) void gemm_tn(
    const float* __restrict__ A, const int* __restrict__ gidx, const float* __restrict__ gtab,
    const float* __restrict__ B0, const float* __restrict__ B1, int nsplitB,
    const float* __restrict__ bias0, const float* __restrict__ bias1, int nsplitBias,
    float* __restrict__ C, int M, int N, int K)
{
  __shared__ float As[16][132];
  __shared__ float Bs[16][132];
  const int tid = threadIdx.x;
  const int m0 = blockIdx.y * 128, n0 = blockIdx.x * 128;

  const int lrow = tid >> 1;            // 0..127
  const int lk   = (tid & 1) * 8;       // 0 or 8
  const float* arow;
  if (GATHER) arow = gtab + (size_t)gidx[m0 + lrow] * K + lk;
  else        arow = A + (size_t)(m0 + lrow) * K + lk;
  const int bn = n0 + lrow;
  const float* brow = ((bn < nsplitB) ? (B0 + (size_t)bn * K)
                                      : (B1 + (size_t)(bn - nsplitB) * K)) + lk;

  const int tx = tid & 15, ty = tid >> 4;

  float bb[2][4];
#pragma unroll
  for (int in = 0; in < 2; ++in)
#pragma unroll
    for (int j = 0; j < 4; ++j) bb[in][j] = 0.f;
  if (bias0) {
#pragma unroll
    for (int in = 0; in < 2; ++in)
#pragma unroll
      for (int j = 0; j < 4; ++j) {
        int n = n0 + in * 64 + tx * 4 + j;
        bb[in][j] = (n < nsplitBias) ? bias0[n] : bias1[n - nsplitBias];
      }
  }

  float acc[2][2][4][4];
#pragma unroll
  for (int im = 0; im < 2; ++im)
#pragma unroll
    for (int in = 0; in < 2; ++in)
#pragma unroll
      for (int i = 0; i < 4; ++i)
#pragma unroll
        for (int j = 0; j < 4; ++j)
          acc[im][in][i][j] = BIASFIRST ? bb[in][j] : 0.f;

  float4 pa0 = *(const float4*)(arow);
  float4 pa1 = *(const float4*)(arow + 4);
  float4 pb0 = *(const float4*)(brow);
  float4 pb1 = *(const float4*)(brow + 4);

  int k0 = 0;
  while (true) {
    __syncthreads();
    As[lk + 0][lrow] = pa0.x; As[lk + 1][lrow] = pa0.y;
    As[lk + 2][lrow] = pa0.z; As[lk + 3][lrow] = pa0.w;
    As[lk + 4][lrow] = pa1.x; As[lk + 5][lrow] = pa1.y;
    As[lk + 6][lrow] = pa1.z; As[lk + 7][lrow] = pa1.w;
    Bs[lk + 0][lrow] = pb0.x; Bs[lk + 1][lrow] = pb0.y;
    Bs[lk + 2][lrow] = pb0.z; Bs[lk + 3][lrow] = pb0.w;
    Bs[lk + 4][lrow] = pb1.x; Bs[lk + 5][lrow] = pb1.y;
    Bs[lk + 6][lrow] = pb1.z; Bs[lk + 7][lrow] = pb1.w;
    __syncthreads();

    k0 += 16;
    const bool more = (k0 < K);
    if (more) {
      pa0 = *(const float4*)(arow + k0);
      pa1 = *(const float4*)(arow + k0 + 4);
      pb0 = *(const float4*)(brow + k0);
      pb1 = *(const float4*)(brow + k0 + 4);
    }

#pragma unroll
    for (int k = 0; k < 16; ++k) {
      const float4 av0 = *(const float4*)&As[k][ty * 4];
      const float4 av1 = *(const float4*)&As[k][64 + ty * 4];
      const float4 bv0 = *(const float4*)&Bs[k][tx * 4];
      const float4 bv1 = *(const float4*)&Bs[k][64 + tx * 4];
      const float am[2][4] = {{av0.x, av0.y, av0.z, av0.w},
                              {av1.x, av1.y, av1.z, av1.w}};
      const float bw[2][4] = {{bv0.x, bv0.y, bv0.z, bv0.w},
                              {bv1.x, bv1.y, bv1.z, bv1.w}};
#pragma unroll
      for (int im = 0; im < 2; ++im)
#pragma unroll
        for (int in = 0; in < 2; ++in)
#pragma unroll
          for (int i = 0; i < 4; ++i)
#pragma unroll
            for (int j = 0; j < 4; ++j)
              acc[im][in][i][j] += am[im][i] * bw[in][j];
    }
    if (!more) break;
  }

#pragma unroll
  for (int im = 0; im < 2; ++im)
#pragma unroll
    for (int i = 0; i < 4; ++i) {
      const int m = m0 + im * 64 + ty * 4 + i;
#pragma unroll
      for (int in = 0; in < 2; ++in) {
        float4 o;
        o.x = acc[im][in][i][0] + (BIASFIRST ? 0.f : bb[in][0]);
        o.y = acc[im][in][i][1] + (BIASFIRST ? 0.f : bb[in][1]);
        o.z = acc[im][in][i][2] + (BIASFIRST ? 0.f : bb[in][2]);
        o.w = acc[im][in][i][3] + (BIASFIRST ? 0.f : bb[in][3]);
        *(float4*)&C[(size_t)m * N + n0 + in * 64 + tx * 4] = o;
      }
    }
}

// ---------------------------------------------------------------------------
// BiLSTM recurrence: QUARTER-split. Each chain (d,b) is spread over 4 WGs of
// 256 threads; each WG owns 64 elements x 4 gates = 256 rows, one row per
// thread, FULL k-range 0..256 in w4[64] (identical accumulation chain ->
// bit-identical gates). __launch_bounds__(256,1) allows ~290 VGPRs resident
// (1 wave/SIMD) -> NO scratch spill (the 512-thread version was capped at
// 256 VGPRs and spilled part of w4 into the serial MAC chain).
// Exchange: same tagged-qword hxbuf protocol; each WG polls the 192 peer
// elements. All per-step barriers are LDS-only (hxbuf tag+value travel in
// one 64-bit atomic -> no global ordering needed).
// Grid 256 WGs = 1 per CU (4 waves/CU) -> co-resident, same contract as the
// previous 128-WG version.
// ---------------------------------------------------------------------------
__global__ __launch_bounds__(256, 1) void lstm_esplit(
    const float* __restrict__ Xg,
    const float* __restrict__ Whh_f, const float* __restrict__ Whh_b,
    unsigned long long* __restrict__ hxbuf,  // [2 parity][64 chain][256] qwords
    float* __restrict__ blstm)
{
  const int tid = threadIdx.x;
  const int pid = blockIdx.x;
  const int q = pid >> 6, chain = pid & 63;   // quarter q owns elems [q*64, q*64+64)
  const int d = chain >> 5, b = chain & 31;
  const int j = tid & 63;               // element within own quarter
  const int g = tid >> 6;               // gate 0=i,1=f,2=g,3=o
  const int elem = q * 64 + j;          // element 0..255
  const int grow = g * 256 + elem;      // global gate row 0..1023

  const float* W = (d ? Whh_b : Whh_f) + (size_t)grow * 256;
  float4 w4[64];
#pragma unroll
  for (int i = 0; i < 64; ++i) w4[i] = *(const float4*)(W + 4 * i);

  __shared__ float h_lds[HIDN];
  __shared__ float gsL[256];
  float creg = 0.f;                     // cell for element `elem` (threads tid<64)
  h_lds[tid] = 0.f;                     // 256 threads cover HIDN=256
  __syncthreads();

  const float4* h4 = (const float4*)h_lds;
  // peer element index for polling: tid<192 covers the 192 non-own elements
  const int pe = (tid < q * 64) ? tid : (tid + 64);
  const size_t xgoff = (size_t)d * 1024 + grow;

  for (int it = 0; it < SEQB; ++it) {
    const int t = d ? (SEQB - 1 - it) : it;
    const size_t m = (size_t)t * BATCH + b;
    const float xv = Xg[m * 2048 + xgoff];   // overlaps the poll below

    // --- poll 192 peer elements (tag == it; zero-init covers it=0) ---
    if (tid < 192) {
      const unsigned long long* src =
          &hxbuf[((size_t)(it & 1) * 64 + chain) * 256 + pe];
      unsigned long long qv;
      do { qv = __hip_atomic_load(src, __ATOMIC_RELAXED, SCOPE_AGENT); }
      while ((unsigned)(qv >> 32) != (unsigned)it);
      h_lds[pe] = __uint_as_float((unsigned)qv);
    }
    barrier_lds();

    // --- full MAC, straight-line, constant w4 indices (bit-identical) ---
    float a0 = 0.f, a1 = 0.f, a2 = 0.f, a3 = 0.f;
#pragma unroll
    for (int i = 0; i < 64; ++i) {
      const float4 hv = h4[i];               // wave-uniform -> LDS broadcast
      const float4 wv = w4[i];
      a0 += wv.x * hv.x; a1 += wv.y * hv.y; a2 += wv.z * hv.z; a3 += wv.w * hv.w;
    }
    gsL[tid] = (a0 + a1) + (a2 + a3) + xv;   // row tid = g*64 + j
    barrier_lds();

    // --- cell update for own 64 elements (all gates LOCAL) ---
    if (tid < 64) {
      const float gi = gsL[tid], gf = gsL[64 + tid];
      const float gg = gsL[128 + tid], go = gsL[192 + tid];
      creg = sigm(gf) * creg + sigm(gi) * tanh_f(gg);
      const float hn = sigm(go) * tanh_f(creg);
      h_lds[elem] = hn;
      const unsigned long long pk =
          ((unsigned long long)(unsigned)(it + 1) << 32) |
          (unsigned long long)__float_as_uint(hn);
      __hip_atomic_store(&hxbuf[((size_t)((it + 1) & 1) * 64 + chain) * 256 + elem], pk,
                         __ATOMIC_RELAXED, SCOPE_AGENT);
      blstm[m * HH2 + (size_t)d * HIDN + elem] = hn;
    }
    barrier_lds();
  }
}

// ---------------------------------------------------------------------------
__global__ __launch_bounds__(256) void attn_k(const float* __restrict__ blstm,
                                              const float* __restrict__ attn_w,
                                              const float* __restrict__ attn_b,
                                              float* __restrict__ attnv)
{
  const int tid = threadIdx.x;
  const int p = blockIdx.x * 4 + (tid >> 6);
  const int lane = tid & 63;
  const size_t base = (size_t)p * HH2 + lane * 8;
  float4 v0 = *(const float4*)&blstm[base];
  float4 v1 = *(const float4*)&blstm[base + 4];
  float4 w0 = *(const float4*)&attn_w[lane * 8];
  float4 w1 = *(const float4*)&attn_w[lane * 8 + 4];
  float acc = v0.x * w0.x + v0.y * w0.y + v0.z * w0.z + v0.w * w0.w
            + v1.x * w1.x + v1.y * w1.y + v1.z * w1.z + v1.w * w1.w;
#pragma unroll
  for (int off = 32; off > 0; off >>= 1) acc += __shfl_down(acc, off);
  if (lane == 0) attnv[p] = acc + attn_b[0];
}

// ---------------------------------------------------------------------------
__global__ __launch_bounds__(64) void entity_prep(const int* __restrict__ spans,
                                                  const float* __restrict__ attnv,
                                                  const float* __restrict__ blstm,
                                                  float* __restrict__ Hent,
                                                  float* __restrict__ P_out)
{
  const int nb = blockIdx.x;
  const int n = nb >> 5, b = nb & 31;
  const int tid = threadIdx.x;
  __shared__ float sc[8];
  if (tid < 8) sc[tid] = attnv[spans[n * 8 + tid] * BATCH + b];
  __syncthreads();
  float mx = sc[0];
#pragma unroll
  for (int w = 1; w < 8; ++w) mx = fmaxf(mx, sc[w]);
  float ex[8]; float ssum = 0.f;
#pragma unroll
  for (int w = 0; w < 8; ++w) { ex[w] = __expf(sc[w] - mx); ssum += ex[w]; }
  float wsum = 0.f;
#pragma unroll
  for (int w = 0; w < 8; ++w) wsum += ex[w] / ssum;
  const size_t base = ((size_t)n * BATCH + b) * HH2;
#pragma unroll
  for (int q = 0; q < 2; ++q) {
    int j = q * 256 + tid * 4;
    float4 v = *(const float4*)&blstm[base + j];
    v.x *= wsum; v.y *= wsum; v.z *= wsum; v.w *= wsum;
    *(float4*)&Hent[base + j] = v;
  }
  if (tid == 0) {
    P_out[((size_t)b * NNODE + n) * 2 + 0] = 0.001f;
    P_out[((size_t)b * NNODE + n) * 2 + 1] = 0.999f;
  }
}

// ---------------------------------------------------------------------------
__global__ void pack_ucat(const float* __restrict__ U_ioc, const float* __restrict__ Uf,
                          float* __restrict__ Ucat)
{
  int j = blockIdx.x, tid = threadIdx.x;
  for (int k = tid; k < 512; k += 128) {
    float v;
    if (j < 1536)      v = U_ioc[(size_t)j * 1024 + k];
    else if (j < 3072) v = U_ioc[(size_t)(j - 1536) * 1024 + 512 + k];
    else               v = Uf[(size_t)(j - 3072) * 512 + k];
    Ucat[(size_t)j * 512 + k] = v;
  }
}

// ---------------------------------------------------------------------------
__global__ __launch_bounds__(256) void mprep(const float* __restrict__ W1,
                                             const float* __restrict__ b1,
                                             const float* __restrict__ W2,
                                             const float* __restrict__ b2,
                                             float* __restrict__ Mmat,
                                             float* __restrict__ mbv)
{
  const int tid = threadIdx.x;
  for (int j = tid; j < 512; j += 256) {
    float a0 = 0.f, a1 = 0.f;
    for (int m = 0; m < 1024; ++m) {
      float w = W1[(size_t)m * 512 + j];
      a0 += W2[m] * w;
      a1 += W2[1024 + m] * w;
    }
    Mmat[j] = a0; Mmat[512 + j] = a1;
  }
  if (tid < 2) {
    float a = b2[tid];
    for (int m = 0; m < 1024; ++m) a += W2[tid * 1024 + m] * b1[m];
    mbv[tid] = a;
  }
}

// ---------------------------------------------------------------------------
// DAG-LSTM sequential kernel — identical to R3 (3.04 ms measured).
// ---------------------------------------------------------------------------
__global__ __launch_bounds__(512) void dag_seq(
    const int* __restrict__ S, const int* __restrict__ T, const int* __restrict__ EN,
    const int* __restrict__ entsz,
    const float* __restrict__ WE,
    const float* __restrict__ Mmat, const float* __restrict__ mbv,
    float* __restrict__ Tall, float* __restrict__ hbuf,
    uint32_t* head, uint32_t* slotbase, uint32_t* arrive,
    const float* __restrict__ Ucat, float* __restrict__ P_out)
{
  const int tid = threadIdx.x;
  __shared__ int   SL[NSt * BATCH * 2];
  __shared__ int   TLt[NSt * BATCH];
  __shared__ int   ELt[NSt * BATCH];
  __shared__ int   eszL[BATCH];
  __shared__ float MmatL[1024];
  __shared__ float mbvL[2];
  __shared__ float pstL[NNODE];
  __shared__ int   evtofL[NSt];
  __shared__ int   confL[NSt];
  __shared__ float red0[8], red1[8], bcast[2];
  __shared__ uint32_t sslot;

  if (blockIdx.x < NHELP) {
    const int w = blockIdx.x;
    const int row = w * 32 + (tid >> 4);
    const int ks = (tid & 15) * 32;
    float wreg[32];
#pragma unroll
    for (int i = 0; i < 8; ++i) {
      float4 v = *(const float4*)&Ucat[(size_t)row * 512 + ks + i * 4];
      wreg[i * 4 + 0] = v.x; wreg[i * 4 + 1] = v.y; wreg[i * 4 + 2] = v.z; wreg[i * 4 + 3] = v.w;
    }
    uint32_t done = 0;
    const int g = w & 7;
    while (true) {
      if (tid == 0) {
        while (__hip_atomic_load(head, __ATOMIC_RELAXED, SCOPE_AGENT) <= done) {
          __builtin_amdgcn_s_sleep(4);
        }
        __builtin_amdgcn_fence(__ATOMIC_ACQUIRE, "agent");
        sslot = slotbase[done];
      }
      __syncthreads();
      const uint32_t slot = sslot;
      if (slot == TERMEVT) break;
      const float* hv = hbuf + (size_t)done * HH2 + ks;
      float acc = 0.f;
#pragma unroll
      for (int i = 0; i < 8; ++i) {
        float4 v = *(const float4*)&hv[i * 4];
        acc += wreg[i * 4 + 0] * v.x + wreg[i * 4 + 1] * v.y
             + wreg[i * 4 + 2] * v.z + wreg[i * 4 + 3] * v.w;
      }
      acc += __shfl_down(acc, 8);
      acc += __shfl_down(acc, 4);
      acc += __shfl_down(acc, 2);
      acc += __shfl_down(acc, 1);
      if ((tid & 15) == 0) {
        __hip_atomic_store(&Tall[(size_t)slot + row], acc, __ATOMIC_RELAXED, SCOPE_AGENT);
      }
      __syncthreads();
      if (tid == 0) {
        __hip_atomic_fetch_add(&arrive[done * 8 + g], 1u, __ATOMIC_RELEASE, SCOPE_AGENT);
      }
      ++done;
    }
    return;
  }

  // master
  for (int i = tid; i < NSt * BATCH * 2; i += 512) SL[i] = S[i];
  for (int i = tid; i < NSt * BATCH; i += 512) { TLt[i] = T[i]; ELt[i] = EN[i]; }
  for (int i = tid; i < 1024; i += 512) MmatL[i] = Mmat[i];
  if (tid < BATCH) eszL[tid] = entsz[tid];
  if (tid < 2) mbvL[tid] = mbv[tid];
  __syncthreads();

  float c = 0.f;
  uint32_t e = 0;
  for (int b = 0; b < BATCH; ++b) {
    const int esz = eszL[b];
    for (int j = tid; j < NNODE; j += 512) pstL[j] = (j < NEnt) ? 0.999f : 0.f;
    if (tid < NSt) confL[tid] = 0;
    __syncthreads();

    bool  pfok = false;
    float pt0 = 0.f, pt1 = 0.f, pt2 = 0.f, pt3 = 0.f, pt4 = 0.f, pt5 = 0.f, pt6 = 0.f, pt7 = 0.f;
    float pw0 = 0.f, pw1 = 0.f, pw2 = 0.f, pwf = 0.f;

#define PFETCH(sn)                                                              \
    do {                                                                        \
      pfok = false;                                                             \
      if ((sn) < NSt) {                                                         \
        const int sbn_ = (sn) * BATCH + b;                                      \
        const int na0_ = SL[2 * sbn_], na1_ = SL[2 * sbn_ + 1];                 \
        const int nel_ = ELt[sbn_];                                             \
        if (nel_ >= 0) {                                                        \
          const float* nwe_ = WE + (size_t)nel_ * 2048;                         \
          pw0 = nwe_[tid]; pw1 = nwe_[512 + tid]; pw2 = nwe_[1024 + tid];       \
          pwf = nwe_[1536 + tid];                                               \
        }                                                                       \
        const bool ok0_ = (na0_ < NEnt) || (confL[na0_ - NEnt] != 0);           \
        const bool ok1_ = (na1_ < NEnt) || (confL[na1_ - NEnt] != 0);           \
        if (ok0_ && ok1_) {                                                     \
          const size_t ns0_ = ((size_t)na0_ * BATCH + b) * NROWS;               \
          const size_t ns1_ = ((size_t)na1_ * BATCH + b) * NROWS;               \
          pt0 = Tall[ns0_ + tid];               pt1 = Tall[ns1_ + 1536 + tid];  \
          pt2 = Tall[ns0_ + 512 + tid];         pt3 = Tall[ns1_ + 2048 + tid];  \
          pt4 = Tall[ns0_ + 1024 + tid];        pt5 = Tall[ns1_ + 2560 + tid];  \
          pt6 = Tall[ns0_ + 3072 + tid];        pt7 = Tall[ns1_ + 3072 + tid];  \
          pfok = true;                                                          \
        }                                                                       \
      }                                                                         \
    } while (0)

    PFETCH(0);

    for (int s = 0; s < NSt; ++s) {
      const int sb = s * BATCH + b;
      const int a0 = SL[2 * sb], a1 = SL[2 * sb + 1];
      const int tgt = TLt[sb], el = ELt[sb];
      const bool valid = (tgt >= esz) && (el > -1);
      const float pa0 = pstL[a0], pa1 = pstL[a1];
      const bool cond = valid && (pa0 > 0.5f) && (pa1 > 0.5f);
      if (cond) {
        if (!pfok) {
          const int r0 = (a0 >= NEnt) ? (a0 - NEnt) : -1;
          const int r1 = (a1 >= NEnt) ? (a1 - NEnt) : -1;
          if (tid < 8 && r0 >= 0 && !confL[r0]) {
            const uint32_t ev = (uint32_t)evtofL[r0];
            while (__hip_atomic_load(&arrive[ev * 8 + tid], __ATOMIC_RELAXED, SCOPE_AGENT)
                   < (uint32_t)HPG) { __builtin_amdgcn_s_sleep(1); }
          }
          if (tid >= 8 && tid < 16 && r1 >= 0 && !confL[r1]) {
            const uint32_t ev = (uint32_t)evtofL[r1];
            while (__hip_atomic_load(&arrive[ev * 8 + (tid - 8)], __ATOMIC_RELAXED, SCOPE_AGENT)
                   < (uint32_t)HPG) { __builtin_amdgcn_s_sleep(1); }
          }
          __syncthreads();
          if (tid == 0) {
            __builtin_amdgcn_fence(__ATOMIC_ACQUIRE, "agent");
            if (r0 >= 0) confL[r0] = 1;
            if (r1 >= 0) confL[r1] = 1;
          }
          __syncthreads();
          const size_t s0 = ((size_t)a0 * BATCH + b) * NROWS;
          const size_t s1 = ((size_t)a1 * BATCH + b) * NROWS;
          pt0 = Tall[s0 + tid];        pt1 = Tall[s1 + 1536 + tid];
          pt2 = Tall[s0 + 512 + tid];  pt3 = Tall[s1 + 2048 + tid];
          pt4 = Tall[s0 + 1024 + tid]; pt5 = Tall[s1 + 2560 + tid];
          pt6 = Tall[s0 + 3072 + tid]; pt7 = Tall[s1 + 3072 + tid];
        }
        const float ii = pw0 + pt0 + pt1;
        const float oo = pw1 + pt2 + pt3;
        const float ch = pw2 + pt4 + pt5;
        const float f0 = sigm(pwf + pt6);
        const float f1 = sigm(pwf + pt7);
        PFETCH(s + 1);
        float cn = (f0 + f1) * c + sigm(ii) * tanh_f(ch);
        cn = fminf(fmaxf(cn, -100.f), 100.f);
        float hh = sigm(oo) * tanh_f(cn);
        hh = fminf(fmaxf(hh, -100.f), 100.f);
        float l0 = MmatL[tid] * hh, l1 = MmatL[512 + tid] * hh;
#pragma unroll
        for (int off = 32; off > 0; off >>= 1) {
          l0 += __shfl_down(l0, off);
          l1 += __shfl_down(l1, off);
        }
        if ((tid & 63) == 0) { red0[tid >> 6] = l0; red1[tid >> 6] = l1; }
        barrier_lds();
        if (tid == 0) {
          float L0 = mbvL[0], L1 = mbvL[1];
#pragma unroll
          for (int wv = 0; wv < 8; ++wv) { L0 += red0[wv]; L1 += red1[wv]; }
          float mx = fmaxf(L0, L1);
          float e0 = __expf(L0 - mx), e1 = __expf(L1 - mx);
          float inv = 1.f / (e0 + e1);
          const float o0 = e0 * inv, o1 = e1 * inv;
          bcast[0] = o0; bcast[1] = o1;
          pstL[tgt] = o1;
          P_out[((size_t)b * NNODE + tgt) * 2 + 0] = o0;
          P_out[((size_t)b * NNODE + tgt) * 2 + 1] = o1;
        }
        barrier_lds();
        c = cn;
        const bool pub = (bcast[1] > 0.5f) && (tgt < NEnt + 32);
        if (pub) {
          __hip_atomic_store(&hbuf[(size_t)e * HH2 + tid], hh, __ATOMIC_RELAXED, SCOPE_AGENT);
          __syncthreads();   // full drain: hbuf stores from ALL waves must land
          if (tid == 0) {
            evtofL[tgt - NEnt] = (int)e;
            __hip_atomic_store(&slotbase[e], (uint32_t)(((uint32_t)tgt * BATCH + (uint32_t)b) * NROWS),
                               __ATOMIC_RELAXED, SCOPE_AGENT);
            __hip_atomic_store(head, e + 1u, __ATOMIC_RELEASE, SCOPE_AGENT);
          }
          ++e;
          barrier_lds();
        }
      } else {
        PFETCH(s + 1);
        if (tid == 0) {
          const float o0 = valid ? 0.999f : ((tgt < NEnt) ? 0.001f : 0.f);
          const float o1 = valid ? 0.001f : ((tgt < NEnt) ? 0.999f : 0.f);
          if (valid || tgt >= NEnt) {
            P_out[((size_t)b * NNODE + tgt) * 2 + 0] = o0;
            P_out[((size_t)b * NNODE + tgt) * 2 + 1] = o1;
          }
          if (valid) pstL[tgt] = o1;
        }
        barrier_lds();
      }
    }
#undef PFETCH
  }
  if (tid == 0) {
    __hip_atomic_store(&slotbase[e], TERMEVT, __ATOMIC_RELAXED, SCOPE_AGENT);
    __hip_atomic_store(head, e + 1u, __ATOMIC_RELEASE, SCOPE_AGENT);
  }
}

// ---------------------------------------------------------------------------
extern "C" void kernel_launch(void* const* d_in, const int* in_sizes, int n_in,
                              void* d_out, int out_size, void* d_ws, size_t ws_size,
                              hipStream_t stream)
{
  const int* tokens = (const int*)d_in[0];
  const int* spans  = (const int*)d_in[1];
  const int* enames = (const int*)d_in[2];
  const int* T      = (const int*)d_in[5];
  const int* S      = (const int*)d_in[6];
  const int* entsz  = (const int*)d_in[7];
  const float* word_emb = (const float*)d_in[8];
  const float* elem_emb = (const float*)d_in[9];
  const float* attn_w = (const float*)d_in[10];
  const float* attn_b = (const float*)d_in[11];
  const float* Wih_f = (const float*)d_in[12];
  const float* Whh_f = (const float*)d_in[13];
  const float* bl_f  = (const float*)d_in[14];
  const float* Wih_b = (const float*)d_in[15];
  const float* Whh_b = (const float*)d_in[16];
  const float* bl_b  = (const float*)d_in[17];
  const float* W_ioc = (const float*)d_in[18];
  const float* U_ioc = (const float*)d_in[19];
  const float* b_ioc = (const float*)d_in[20];
  const float* Wf    = (const float*)d_in[21];
  const float* Uf    = (const float*)d_in[22];
  const float* bf    = (const float*)d_in[23];
  const float* W1    = (const float*)d_in[24];
  const float* b1    = (const float*)d_in[25];
  const float* W2    = (const float*)d_in[26];
  const float* b2    = (const float*)d_in[27];
  float* P_out = (float*)d_out;

  char* ws = (char*)d_ws;
  uint32_t* head     = (uint32_t*)ws;                    // @0
  uint32_t* slotbase = (uint32_t*)(ws + 8192);           // 1024 u32
  uint32_t* arrive   = (uint32_t*)(ws + 16384);          // 8*1024 u32 = 32KB
  float* fws = (float*)(ws + 65536);
  size_t off = 0;
  float* Xg    = fws + off; off += (size_t)16384 * 2048;
  float* blstm = fws + off; off += (size_t)SEQB * BATCH * HH2;
  float* attnv = fws + off; off += (size_t)SEQB * BATCH;
  float* Hent  = fws + off; off += (size_t)2048 * 512;
  float* Tall  = fws + off; off += (size_t)96 * BATCH * NROWS;
  unsigned long long* hxbuf = (unsigned long long*)(fws + off);
  off += (size_t)2 * 64 * 256 * 2;           // qwords = 2 floats each
  float* Ucat  = fws + off; off += (size_t)NROWS * 512;
  float* WE    = fws + off; off += (size_t)128 * 2048;   // [el][1536 ioc | 512 f]
  float* Mmat  = fws + off; off += 1024;
  float* mbv   = fws + off; off += 16;
  float* hbuf  = fws + off; off += (size_t)1024 * 512;
  const size_t needed = 65536 + off * sizeof(float);
  if (ws_size < needed) return;   // workspace too small: bail (visible failure)

  hipMemsetAsync(d_ws, 0, 65536, stream);
  // hxbuf must start as tag=0/value=0 (valid "h=0 at step 0" records)
  hipMemsetAsync(hxbuf, 0, (size_t)2 * 64 * 256 * 8, stream);

  // 1) Xg = gather(word_emb, tokens) @ [Wih_f;Wih_b].T + [bl_f;bl_b]
  gemm_tn<1, 0><<<dim3(2048 / 128, 16384 / 128), 256, 0, stream>>>(
      nullptr, tokens, word_emb, Wih_f, Wih_b, 1024, bl_f, bl_b, 1024,
      Xg, 16384, 2048, 256);

  // 2) recurrent BiLSTM (quarter-split, tagged h exchange, resident weights)
  lstm_esplit<<<256, 256, 0, stream>>>(Xg, Whh_f, Whh_b, hxbuf, blstm);

  // 3) attention scores + entity H
  attn_k<<<4096, 256, 0, stream>>>(blstm, attn_w, attn_b, attnv);
  entity_prep<<<2048, 64, 0, stream>>>(spans, attnv, blstm, Hent, P_out);

  // 4) DAG-LSTM precompute
  pack_ucat<<<NROWS, 128, 0, stream>>>(U_ioc, Uf, Ucat);
  // WE[el] = [b_ioc + elem_emb[el] @ W_ioc.T | bf + elem_emb[el] @ Wf.T]
  gemm_tn<0, 1><<<dim3(2048 / 128, 1), 256, 0, stream>>>(
      elem_emb, nullptr, nullptr, W_ioc, Wf, 1536, b_ioc, bf, 1536,
      WE, 128, 2048, 128);
  mprep<<<1, 256, 0, stream>>>(W1, b1, W2, b2, Mmat, mbv);
  gemm_tn<0, 0><<<dim3(NROWS / 128, 2048 / 128), 256, 0, stream>>>(
      Hent, nullptr, nullptr, Ucat, nullptr, 0x40000000, nullptr, nullptr, 0,
      Tall, 2048, NROWS, 512);

  // 5) sequential DAG-LSTM with helper projection grid
  dag_seq<<<NHELP + 1, 512, 0, stream>>>(S, T, enames, entsz, WE, Mmat, mbv,
                                         Tall, hbuf, head, slotbase, arrive, Ucat, P_out);
}

// Round 5
// 5461.862 us; speedup vs baseline: 1.2614x; 1.0050x over previous
//
#include <hip/hip_runtime.h>
#include <stdint.h>

#define SEQB 512
#define BATCH 32
#define EDIM 256
#define HIDN 256
#define HH2 512
#define RDIM 128
#define NEnt 64
#define NSt 64
#define NNODE 128
#define NHELP 112
#define HPG 14          // helpers per arrive-group (112/8)
#define NROWS 3584      // 1536 (U0) + 1536 (U1) + 512 (Uf)
#define TERMEVT 0xFFFFFFFFu
#define SCOPE_AGENT __HIP_MEMORY_SCOPE_AGENT

static __device__ __forceinline__ float sigm(float x) { return 1.0f / (1.0f + __expf(-x)); }
static __device__ __forceinline__ float tanh_f(float x) { return 1.0f - 2.0f / (__expf(2.0f * x) + 1.0f); }

// Barrier that drains ONLY LDS (lgkmcnt), leaving global loads/stores in
// flight across the barrier. __syncthreads() would emit s_waitcnt vmcnt(0)
// lgkmcnt(0) and serialize every prefetch load / output store at LLC latency.
// Use ONLY where no cross-thread data flows through GLOBAL memory.
static __device__ __forceinline__ void barrier_lds() {
  asm volatile("s_waitcnt lgkmcnt(0)" ::: "memory");
  __builtin_amdgcn_sched_barrier(0);
  __builtin_amdgcn_s_barrier();
}

// ---------------------------------------------------------------------------
// Tiled fp32 GEMM: C[m][n] = sum_k Arow(m)[k] * Brow(n)[k] (+ bias[n])
// 128x128 tile, 256 threads, 8x8 per thread (4+4 split), register prefetch.
// BIASFIRST=1 initializes the accumulator with bias (bit-identical to a
// "acc = bias; acc += w*e" scalar chain); BIASFIRST=0 adds bias at the end.
// ---------------------------------------------------------------------------
template<int GATHER, int BIASFIRST>
__global__ __launch_bounds__(256) void gemm_tn(
    const float* __restrict__ A, const int* __restrict__ gidx, const float* __restrict__ gtab,
    const float* __restrict__ B0, const float* __restrict__ B1, int nsplitB,
    const float* __restrict__ bias0, const float* __restrict__ bias1, int nsplitBias,
    float* __restrict__ C, int M, int N, int K)
{
  __shared__ float As[16][132];
  __shared__ float Bs[16][132];
  const int tid = threadIdx.x;
  const int m0 = blockIdx.y * 128, n0 = blockIdx.x * 128;

  const int lrow = tid >> 1;            // 0..127
  const int lk   = (tid & 1) * 8;       // 0 or 8
  const float* arow;
  if (GATHER) arow = gtab + (size_t)gidx[m0 + lrow] * K + lk;
  else        arow = A + (size_t)(m0 + lrow) * K + lk;
  const int bn = n0 + lrow;
  const float* brow = ((bn < nsplitB) ? (B0 + (size_t)bn * K)
                                      : (B1 + (size_t)(bn - nsplitB) * K)) + lk;

  const int tx = tid & 15, ty = tid >> 4;

  float bb[2][4];
#pragma unroll
  for (int in = 0; in < 2; ++in)
#pragma unroll
    for (int j = 0; j < 4; ++j) bb[in][j] = 0.f;
  if (bias0) {
#pragma unroll
    for (int in = 0; in < 2; ++in)
#pragma unroll
      for (int j = 0; j < 4; ++j) {
        int n = n0 + in * 64 + tx * 4 + j;
        bb[in][j] = (n < nsplitBias) ? bias0[n] : bias1[n - nsplitBias];
      }
  }

  float acc[2][2][4][4];
#pragma unroll
  for (int im = 0; im < 2; ++im)
#pragma unroll
    for (int in = 0; in < 2; ++in)
#pragma unroll
      for (int i = 0; i < 4; ++i)
#pragma unroll
        for (int j = 0; j < 4; ++j)
          acc[im][in][i][j] = BIASFIRST ? bb[in][j] : 0.f;

  float4 pa0 = *(const float4*)(arow);
  float4 pa1 = *(const float4*)(arow + 4);
  float4 pb0 = *(const float4*)(brow);
  float4 pb1 = *(const float4*)(brow + 4);

  int k0 = 0;
  while (true) {
    __syncthreads();
    As[lk + 0][lrow] = pa0.x; As[lk + 1][lrow] = pa0.y;
    As[lk + 2][lrow] = pa0.z; As[lk + 3][lrow] = pa0.w;
    As[lk + 4][lrow] = pa1.x; As[lk + 5][lrow] = pa1.y;
    As[lk + 6][lrow] = pa1.z; As[lk + 7][lrow] = pa1.w;
    Bs[lk + 0][lrow] = pb0.x; Bs[lk + 1][lrow] = pb0.y;
    Bs[lk + 2][lrow] = pb0.z; Bs[lk + 3][lrow] = pb0.w;
    Bs[lk + 4][lrow] = pb1.x; Bs[lk + 5][lrow] = pb1.y;
    Bs[lk + 6][lrow] = pb1.z; Bs[lk + 7][lrow] = pb1.w;
    __syncthreads();

    k0 += 16;
    const bool more = (k0 < K);
    if (more) {
      pa0 = *(const float4*)(arow + k0);
      pa1 = *(const float4*)(arow + k0 + 4);
      pb0 = *(const float4*)(brow + k0);
      pb1 = *(const float4*)(brow + k0 + 4);
    }

#pragma unroll
    for (int k = 0; k < 16; ++k) {
      const float4 av0 = *(const float4*)&As[k][ty * 4];
      const float4 av1 = *(const float4*)&As[k][64 + ty * 4];
      const float4 bv0 = *(const float4*)&Bs[k][tx * 4];
      const float4 bv1 = *(const float4*)&Bs[k][64 + tx * 4];
      const float am[2][4] = {{av0.x, av0.y, av0.z, av0.w},
                              {av1.x, av1.y, av1.z, av1.w}};
      const float bw[2][4] = {{bv0.x, bv0.y, bv0.z, bv0.w},
                              {bv1.x, bv1.y, bv1.z, bv1.w}};
#pragma unroll
      for (int im = 0; im < 2; ++im)
#pragma unroll
        for (int in = 0; in < 2; ++in)
#pragma unroll
          for (int i = 0; i < 4; ++i)
#pragma unroll
            for (int j = 0; j < 4; ++j)
              acc[im][in][i][j] += am[im][i] * bw[in][j];
    }
    if (!more) break;
  }

#pragma unroll
  for (int im = 0; im < 2; ++im)
#pragma unroll
    for (int i = 0; i < 4; ++i) {
      const int m = m0 + im * 64 + ty * 4 + i;
#pragma unroll
      for (int in = 0; in < 2; ++in) {
        float4 o;
        o.x = acc[im][in][i][0] + (BIASFIRST ? 0.f : bb[in][0]);
        o.y = acc[im][in][i][1] + (BIASFIRST ? 0.f : bb[in][1]);
        o.z = acc[im][in][i][2] + (BIASFIRST ? 0.f : bb[in][2]);
        o.w = acc[im][in][i][3] + (BIASFIRST ? 0.f : bb[in][3]);
        *(float4*)&C[(size_t)m * N + n0 + in * 64 + tx * 4] = o;
      }
    }
}

// ---------------------------------------------------------------------------
// BiLSTM recurrence: QUARTER-split (R3 winner, unchanged).
// ---------------------------------------------------------------------------
__global__ __launch_bounds__(256, 1) void lstm_esplit(
    const float* __restrict__ Xg,
    const float* __restrict__ Whh_f, const float* __restrict__ Whh_b,
    unsigned long long* __restrict__ hxbuf,  // [2 parity][64 chain][256] qwords
    float* __restrict__ blstm)
{
  const int tid = threadIdx.x;
  const int pid = blockIdx.x;
  const int q = pid >> 6, chain = pid & 63;   // quarter q owns elems [q*64, q*64+64)
  const int d = chain >> 5, b = chain & 31;
  const int j = tid & 63;               // element within own quarter
  const int g = tid >> 6;               // gate 0=i,1=f,2=g,3=o
  const int elem = q * 64 + j;          // element 0..255
  const int grow = g * 256 + elem;      // global gate row 0..1023

  const float* W = (d ? Whh_b : Whh_f) + (size_t)grow * 256;
  float4 w4[64];
#pragma unroll
  for (int i = 0; i < 64; ++i) w4[i] = *(const float4*)(W + 4 * i);

  __shared__ float h_lds[HIDN];
  __shared__ float gsL[256];
  float creg = 0.f;                     // cell for element `elem` (threads tid<64)
  h_lds[tid] = 0.f;                     // 256 threads cover HIDN=256
  __syncthreads();

  const float4* h4 = (const float4*)h_lds;
  // peer element index for polling: tid<192 covers the 192 non-own elements
  const int pe = (tid < q * 64) ? tid : (tid + 64);
  const size_t xgoff = (size_t)d * 1024 + grow;

  for (int it = 0; it < SEQB; ++it) {
    const int t = d ? (SEQB - 1 - it) : it;
    const size_t m = (size_t)t * BATCH + b;
    const float xv = Xg[m * 2048 + xgoff];   // overlaps the poll below

    // --- poll 192 peer elements (tag == it; zero-init covers it=0) ---
    if (tid < 192) {
      const unsigned long long* src =
          &hxbuf[((size_t)(it & 1) * 64 + chain) * 256 + pe];
      unsigned long long qv;
      do { qv = __hip_atomic_load(src, __ATOMIC_RELAXED, SCOPE_AGENT); }
      while ((unsigned)(qv >> 32) != (unsigned)it);
      h_lds[pe] = __uint_as_float((unsigned)qv);
    }
    barrier_lds();

    // --- full MAC, straight-line, constant w4 indices (bit-identical) ---
    float a0 = 0.f, a1 = 0.f, a2 = 0.f, a3 = 0.f;
#pragma unroll
    for (int i = 0; i < 64; ++i) {
      const float4 hv = h4[i];               // wave-uniform -> LDS broadcast
      const float4 wv = w4[i];
      a0 += wv.x * hv.x; a1 += wv.y * hv.y; a2 += wv.z * hv.z; a3 += wv.w * hv.w;
    }
    gsL[tid] = (a0 + a1) + (a2 + a3) + xv;   // row tid = g*64 + j
    barrier_lds();

    // --- cell update for own 64 elements (all gates LOCAL) ---
    if (tid < 64) {
      const float gi = gsL[tid], gf = gsL[64 + tid];
      const float gg = gsL[128 + tid], go = gsL[192 + tid];
      creg = sigm(gf) * creg + sigm(gi) * tanh_f(gg);
      const float hn = sigm(go) * tanh_f(creg);
      h_lds[elem] = hn;
      const unsigned long long pk =
          ((unsigned long long)(unsigned)(it + 1) << 32) |
          (unsigned long long)__float_as_uint(hn);
      __hip_atomic_store(&hxbuf[((size_t)((it + 1) & 1) * 64 + chain) * 256 + elem], pk,
                         __ATOMIC_RELAXED, SCOPE_AGENT);
      blstm[m * HH2 + (size_t)d * HIDN + elem] = hn;
    }
    barrier_lds();
  }
}

// ---------------------------------------------------------------------------
__global__ __launch_bounds__(256) void attn_k(const float* __restrict__ blstm,
                                              const float* __restrict__ attn_w,
                                              const float* __restrict__ attn_b,
                                              float* __restrict__ attnv)
{
  const int tid = threadIdx.x;
  const int p = blockIdx.x * 4 + (tid >> 6);
  const int lane = tid & 63;
  const size_t base = (size_t)p * HH2 + lane * 8;
  float4 v0 = *(const float4*)&blstm[base];
  float4 v1 = *(const float4*)&blstm[base + 4];
  float4 w0 = *(const float4*)&attn_w[lane * 8];
  float4 w1 = *(const float4*)&attn_w[lane * 8 + 4];
  float acc = v0.x * w0.x + v0.y * w0.y + v0.z * w0.z + v0.w * w0.w
            + v1.x * w1.x + v1.y * w1.y + v1.z * w1.z + v1.w * w1.w;
#pragma unroll
  for (int off = 32; off > 0; off >>= 1) acc += __shfl_down(acc, off);
  if (lane == 0) attnv[p] = acc + attn_b[0];
}

// ---------------------------------------------------------------------------
__global__ __launch_bounds__(64) void entity_prep(const int* __restrict__ spans,
                                                  const float* __restrict__ attnv,
                                                  const float* __restrict__ blstm,
                                                  float* __restrict__ Hent,
                                                  float* __restrict__ P_out)
{
  const int nb = blockIdx.x;
  const int n = nb >> 5, b = nb & 31;
  const int tid = threadIdx.x;
  __shared__ float sc[8];
  if (tid < 8) sc[tid] = attnv[spans[n * 8 + tid] * BATCH + b];
  __syncthreads();
  float mx = sc[0];
#pragma unroll
  for (int w = 1; w < 8; ++w) mx = fmaxf(mx, sc[w]);
  float ex[8]; float ssum = 0.f;
#pragma unroll
  for (int w = 0; w < 8; ++w) { ex[w] = __expf(sc[w] - mx); ssum += ex[w]; }
  float wsum = 0.f;
#pragma unroll
  for (int w = 0; w < 8; ++w) wsum += ex[w] / ssum;
  const size_t base = ((size_t)n * BATCH + b) * HH2;
#pragma unroll
  for (int q = 0; q < 2; ++q) {
    int j = q * 256 + tid * 4;
    float4 v = *(const float4*)&blstm[base + j];
    v.x *= wsum; v.y *= wsum; v.z *= wsum; v.w *= wsum;
    *(float4*)&Hent[base + j] = v;
  }
  if (tid == 0) {
    P_out[((size_t)b * NNODE + n) * 2 + 0] = 0.001f;
    P_out[((size_t)b * NNODE + n) * 2 + 1] = 0.999f;
  }
}

// ---------------------------------------------------------------------------
__global__ void pack_ucat(const float* __restrict__ U_ioc, const float* __restrict__ Uf,
                          float* __restrict__ Ucat)
{
  int j = blockIdx.x, tid = threadIdx.x;
  for (int k = tid; k < 512; k += 128) {
    float v;
    if (j < 1536)      v = U_ioc[(size_t)j * 1024 + k];
    else if (j < 3072) v = U_ioc[(size_t)(j - 1536) * 1024 + 512 + k];
    else               v = Uf[(size_t)(j - 3072) * 512 + k];
    Ucat[(size_t)j * 512 + k] = v;
  }
}

// ---------------------------------------------------------------------------
__global__ __launch_bounds__(256) void mprep(const float* __restrict__ W1,
                                             const float* __restrict__ b1,
                                             const float* __restrict__ W2,
                                             const float* __restrict__ b2,
                                             float* __restrict__ Mmat,
                                             float* __restrict__ mbv)
{
  const int tid = threadIdx.x;
  for (int j = tid; j < 512; j += 256) {
    float a0 = 0.f, a1 = 0.f;
    for (int m = 0; m < 1024; ++m) {
      float w = W1[(size_t)m * 512 + j];
      a0 += W2[m] * w;
      a1 += W2[1024 + m] * w;
    }
    Mmat[j] = a0; Mmat[512 + j] = a1;
  }
  if (tid < 2) {
    float a = b2[tid];
    for (int m = 0; m < 1024; ++m) a += W2[tid * 1024 + m] * b1[m];
    mbv[tid] = a;
  }
}

// ---------------------------------------------------------------------------
// DAG-LSTM sequential kernel. R4 changes (master only, helpers untouched):
//  (a) redundant softmax: ALL threads read red[fp][8]+mbv after the single
//      gather barrier and compute L0/L1/softmax identically (IEEE-determin-
//      istic -> same o0/o1 everywhere). Removes barrier #2 + tid0 serial
//      section + bcast. red[] parity-double-buffered: adjacent fast steps
//      use different buffers; the intervening fast step's barrier separates
//      same-parity reuse, so one barrier per fast step is safe.
//  (b) zero-barrier else path: each wave's lane-0 writes pstL[tgt] itself
//      (same value everywhere; DS ops are per-wave in-order, so every wave
//      sees exactly the writes of steps < s -> cond stays uniform). Waves
//      may drift across else steps; batch-start barrier protects the re-init.
//  (c) ordered-event cascade: helpers complete events strictly in order, so
//      a full arrive[ev] implies all events <= ev are done. The (rare) slow
//      path confirms EVERY published node with evtofL[r] <= waited event.
//      Requires per-batch evtofL=-1 init so stale events can't leak.
// ---------------------------------------------------------------------------
__global__ __launch_bounds__(512) void dag_seq(
    const int* __restrict__ S, const int* __restrict__ T, const int* __restrict__ EN,
    const int* __restrict__ entsz,
    const float* __restrict__ WE,
    const float* __restrict__ Mmat, const float* __restrict__ mbv,
    float* __restrict__ Tall, float* __restrict__ hbuf,
    uint32_t* head, uint32_t* slotbase, uint32_t* arrive,
    const float* __restrict__ Ucat, float* __restrict__ P_out)
{
  const int tid = threadIdx.x;
  __shared__ int   SL[NSt * BATCH * 2];
  __shared__ int   TLt[NSt * BATCH];
  __shared__ int   ELt[NSt * BATCH];
  __shared__ int   eszL[BATCH];
  __shared__ float MmatL[1024];
  __shared__ float mbvL[2];
  __shared__ float pstL[NNODE];
  __shared__ int   evtofL[NSt];
  __shared__ int   confL[NSt];
  __shared__ float red0[2][8], red1[2][8];
  __shared__ uint32_t sslot;

  if (blockIdx.x < NHELP) {
    const int w = blockIdx.x;
    const int row = w * 32 + (tid >> 4);
    const int ks = (tid & 15) * 32;
    float wreg[32];
#pragma unroll
    for (int i = 0; i < 8; ++i) {
      float4 v = *(const float4*)&Ucat[(size_t)row * 512 + ks + i * 4];
      wreg[i * 4 + 0] = v.x; wreg[i * 4 + 1] = v.y; wreg[i * 4 + 2] = v.z; wreg[i * 4 + 3] = v.w;
    }
    uint32_t done = 0;
    const int g = w & 7;
    while (true) {
      if (tid == 0) {
        while (__hip_atomic_load(head, __ATOMIC_RELAXED, SCOPE_AGENT) <= done) {
          __builtin_amdgcn_s_sleep(4);
        }
        __builtin_amdgcn_fence(__ATOMIC_ACQUIRE, "agent");
        sslot = slotbase[done];
      }
      __syncthreads();
      const uint32_t slot = sslot;
      if (slot == TERMEVT) break;
      const float* hv = hbuf + (size_t)done * HH2 + ks;
      float acc = 0.f;
#pragma unroll
      for (int i = 0; i < 8; ++i) {
        float4 v = *(const float4*)&hv[i * 4];
        acc += wreg[i * 4 + 0] * v.x + wreg[i * 4 + 1] * v.y
             + wreg[i * 4 + 2] * v.z + wreg[i * 4 + 3] * v.w;
      }
      acc += __shfl_down(acc, 8);
      acc += __shfl_down(acc, 4);
      acc += __shfl_down(acc, 2);
      acc += __shfl_down(acc, 1);
      if ((tid & 15) == 0) {
        __hip_atomic_store(&Tall[(size_t)slot + row], acc, __ATOMIC_RELAXED, SCOPE_AGENT);
      }
      __syncthreads();
      if (tid == 0) {
        __hip_atomic_fetch_add(&arrive[done * 8 + g], 1u, __ATOMIC_RELEASE, SCOPE_AGENT);
      }
      ++done;
    }
    return;
  }

  // master
  for (int i = tid; i < NSt * BATCH * 2; i += 512) SL[i] = S[i];
  for (int i = tid; i < NSt * BATCH; i += 512) { TLt[i] = T[i]; ELt[i] = EN[i]; }
  for (int i = tid; i < 1024; i += 512) MmatL[i] = Mmat[i];
  if (tid < BATCH) eszL[tid] = entsz[tid];
  if (tid < 2) mbvL[tid] = mbv[tid];
  __syncthreads();

  float c = 0.f;
  uint32_t e = 0;
  for (int b = 0; b < BATCH; ++b) {
    barrier_lds();    // laggard waves (barrier-less else steps) must finish
                      // reading pstL before the re-init below
    const int esz = eszL[b];
    for (int j = tid; j < NNODE; j += 512) pstL[j] = (j < NEnt) ? 0.999f : 0.f;
    if (tid < NSt) { confL[tid] = 0; evtofL[tid] = -1; }
    __syncthreads();
    int fp = 0;       // fast-step parity for red[] double-buffer

    bool  pfok = false;
    float pt0 = 0.f, pt1 = 0.f, pt2 = 0.f, pt3 = 0.f, pt4 = 0.f, pt5 = 0.f, pt6 = 0.f, pt7 = 0.f;
    float pw0 = 0.f, pw1 = 0.f, pw2 = 0.f, pwf = 0.f;

#define PFETCH(sn)                                                              \
    do {                                                                        \
      pfok = false;                                                             \
      if ((sn) < NSt) {                                                         \
        const int sbn_ = (sn) * BATCH + b;                                      \
        const int na0_ = SL[2 * sbn_], na1_ = SL[2 * sbn_ + 1];                 \
        const int nel_ = ELt[sbn_];                                             \
        if (nel_ >= 0) {                                                        \
          const float* nwe_ = WE + (size_t)nel_ * 2048;                         \
          pw0 = nwe_[tid]; pw1 = nwe_[512 + tid]; pw2 = nwe_[1024 + tid];       \
          pwf = nwe_[1536 + tid];                                               \
        }                                                                       \
        const bool ok0_ = (na0_ < NEnt) || (confL[na0_ - NEnt] != 0);           \
        const bool ok1_ = (na1_ < NEnt) || (confL[na1_ - NEnt] != 0);           \
        if (ok0_ && ok1_) {                                                     \
          const size_t ns0_ = ((size_t)na0_ * BATCH + b) * NROWS;               \
          const size_t ns1_ = ((size_t)na1_ * BATCH + b) * NROWS;               \
          pt0 = Tall[ns0_ + tid];               pt1 = Tall[ns1_ + 1536 + tid];  \
          pt2 = Tall[ns0_ + 512 + tid];         pt3 = Tall[ns1_ + 2048 + tid];  \
          pt4 = Tall[ns0_ + 1024 + tid];        pt5 = Tall[ns1_ + 2560 + tid];  \
          pt6 = Tall[ns0_ + 3072 + tid];        pt7 = Tall[ns1_ + 3072 + tid];  \
          pfok = true;                                                          \
        }                                                                       \
      }                                                                         \
    } while (0)

    PFETCH(0);

    for (int s = 0; s < NSt; ++s) {
      const int sb = s * BATCH + b;
      const int a0 = SL[2 * sb], a1 = SL[2 * sb + 1];
      const int tgt = TLt[sb], el = ELt[sb];
      const bool valid = (tgt >= esz) && (el > -1);
      const float pa0 = pstL[a0], pa1 = pstL[a1];
      const bool cond = valid && (pa0 > 0.5f) && (pa1 > 0.5f);
      if (cond) {
        if (!pfok) {
          const int r0 = (a0 >= NEnt) ? (a0 - NEnt) : -1;
          const int r1 = (a1 >= NEnt) ? (a1 - NEnt) : -1;
          if (tid < 8 && r0 >= 0 && !confL[r0]) {
            const uint32_t ev = (uint32_t)evtofL[r0];
            while (__hip_atomic_load(&arrive[ev * 8 + tid], __ATOMIC_RELAXED, SCOPE_AGENT)
                   < (uint32_t)HPG) { __builtin_amdgcn_s_sleep(1); }
          }
          if (tid >= 8 && tid < 16 && r1 >= 0 && !confL[r1]) {
            const uint32_t ev = (uint32_t)evtofL[r1];
            while (__hip_atomic_load(&arrive[ev * 8 + (tid - 8)], __ATOMIC_RELAXED, SCOPE_AGENT)
                   < (uint32_t)HPG) { __builtin_amdgcn_s_sleep(1); }
          }
          __syncthreads();
          if (tid == 0) {
            __builtin_amdgcn_fence(__ATOMIC_ACQUIRE, "agent");
            int evm = -1;
            if (r0 >= 0) { confL[r0] = 1; if (evtofL[r0] > evm) evm = evtofL[r0]; }
            if (r1 >= 0) { confL[r1] = 1; if (evtofL[r1] > evm) evm = evtofL[r1]; }
            // helpers complete events strictly in order: a full arrive[evm]
            // (or prior confirmation) implies all events <= evm are done.
            if (evm >= 0) {
              for (int r = 0; r < 32; ++r) {
                const int ev_ = evtofL[r];
                if (ev_ >= 0 && ev_ <= evm) confL[r] = 1;
              }
            }
          }
          __syncthreads();
          const size_t s0 = ((size_t)a0 * BATCH + b) * NROWS;
          const size_t s1 = ((size_t)a1 * BATCH + b) * NROWS;
          pt0 = Tall[s0 + tid];        pt1 = Tall[s1 + 1536 + tid];
          pt2 = Tall[s0 + 512 + tid];  pt3 = Tall[s1 + 2048 + tid];
          pt4 = Tall[s0 + 1024 + tid]; pt5 = Tall[s1 + 2560 + tid];
          pt6 = Tall[s0 + 3072 + tid]; pt7 = Tall[s1 + 3072 + tid];
        }
        const float ii = pw0 + pt0 + pt1;
        const float oo = pw1 + pt2 + pt3;
        const float ch = pw2 + pt4 + pt5;
        const float f0 = sigm(pwf + pt6);
        const float f1 = sigm(pwf + pt7);
        PFETCH(s + 1);
        float cn = (f0 + f1) * c + sigm(ii) * tanh_f(ch);
        cn = fminf(fmaxf(cn, -100.f), 100.f);
        float hh = sigm(oo) * tanh_f(cn);
        hh = fminf(fmaxf(hh, -100.f), 100.f);
        float l0 = MmatL[tid] * hh, l1 = MmatL[512 + tid] * hh;
#pragma unroll
        for (int off = 32; off > 0; off >>= 1) {
          l0 += __shfl_down(l0, off);
          l1 += __shfl_down(l1, off);
        }
        if ((tid & 63) == 0) { red0[fp][tid >> 6] = l0; red1[fp][tid >> 6] = l1; }
        barrier_lds();
        // redundant softmax: identical FP ops on identical LDS inputs in
        // every thread -> bit-identical o0/o1 everywhere, no bcast needed.
        float L0 = mbvL[0], L1 = mbvL[1];
#pragma unroll
        for (int wv = 0; wv < 8; ++wv) { L0 += red0[fp][wv]; L1 += red1[fp][wv]; }
        const float mx = fmaxf(L0, L1);
        const float e0 = __expf(L0 - mx), e1 = __expf(L1 - mx);
        const float inv = 1.f / (e0 + e1);
        const float o0 = e0 * inv, o1 = e1 * inv;
        if ((tid & 63) == 0) pstL[tgt] = o1;   // per-wave write: DS in-order
        if (tid == 0) {
          P_out[((size_t)b * NNODE + tgt) * 2 + 0] = o0;
          P_out[((size_t)b * NNODE + tgt) * 2 + 1] = o1;
        }
        fp ^= 1;
        c = cn;
        const bool pub = (o1 > 0.5f) && (tgt < NEnt + 32);
        if (pub) {
          __hip_atomic_store(&hbuf[(size_t)e * HH2 + tid], hh, __ATOMIC_RELAXED, SCOPE_AGENT);
          __syncthreads();   // full drain: hbuf stores from ALL waves must land
          if (tid == 0) {
            evtofL[tgt - NEnt] = (int)e;
            __hip_atomic_store(&slotbase[e], (uint32_t)(((uint32_t)tgt * BATCH + (uint32_t)b) * NROWS),
                               __ATOMIC_RELAXED, SCOPE_AGENT);
            __hip_atomic_store(head, e + 1u, __ATOMIC_RELEASE, SCOPE_AGENT);
          }
          ++e;
          barrier_lds();     // evtofL visible before any later slow-path read
        }
      } else {
        PFETCH(s + 1);
        if (tid == 0 && (valid || tgt >= NEnt)) {
          const float o0 = valid ? 0.999f : ((tgt < NEnt) ? 0.001f : 0.f);
          const float o1 = valid ? 0.001f : ((tgt < NEnt) ? 0.999f : 0.f);
          P_out[((size_t)b * NNODE + tgt) * 2 + 0] = o0;
          P_out[((size_t)b * NNODE + tgt) * 2 + 1] = o1;
        }
        if (valid && (tid & 63) == 0) pstL[tgt] = 0.001f;
        // no barrier: every wave wrote the value itself (DS per-wave
        // in-order), and all waves write identical values -> each wave's
        // view of pstL at step s is exactly the writes of steps < s.
      }
    }
#undef PFETCH
  }
  if (tid == 0) {
    __hip_atomic_store(&slotbase[e], TERMEVT, __ATOMIC_RELAXED, SCOPE_AGENT);
    __hip_atomic_store(head, e + 1u, __ATOMIC_RELEASE, SCOPE_AGENT);
  }
}

// ---------------------------------------------------------------------------
extern "C" void kernel_launch(void* const* d_in, const int* in_sizes, int n_in,
                              void* d_out, int out_size, void* d_ws, size_t ws_size,
                              hipStream_t stream)
{
  const int* tokens = (const int*)d_in[0];
  const int* spans  = (const int*)d_in[1];
  const int* enames = (const int*)d_in[2];
  const int* T      = (const int*)d_in[5];
  const int* S      = (const int*)d_in[6];
  const int* entsz  = (const int*)d_in[7];
  const float* word_emb = (const float*)d_in[8];
  const float* elem_emb = (const float*)d_in[9];
  const float* attn_w = (const float*)d_in[10];
  const float* attn_b = (const float*)d_in[11];
  const float* Wih_f = (const float*)d_in[12];
  const float* Whh_f = (const float*)d_in[13];
  const float* bl_f  = (const float*)d_in[14];
  const float* Wih_b = (const float*)d_in[15];
  const float* Whh_b = (const float*)d_in[16];
  const float* bl_b  = (const float*)d_in[17];
  const float* W_ioc = (const float*)d_in[18];
  const float* U_ioc = (const float*)d_in[19];
  const float* b_ioc = (const float*)d_in[20];
  const float* Wf    = (const float*)d_in[21];
  const float* Uf    = (const float*)d_in[22];
  const float* bf    = (const float*)d_in[23];
  const float* W1    = (const float*)d_in[24];
  const float* b1    = (const float*)d_in[25];
  const float* W2    = (const float*)d_in[26];
  const float* b2    = (const float*)d_in[27];
  float* P_out = (float*)d_out;

  char* ws = (char*)d_ws;
  uint32_t* head     = (uint32_t*)ws;                    // @0
  uint32_t* slotbase = (uint32_t*)(ws + 8192);           // 1024 u32
  uint32_t* arrive   = (uint32_t*)(ws + 16384);          // 8*1024 u32 = 32KB
  float* fws = (float*)(ws + 65536);
  size_t off = 0;
  float* Xg    = fws + off; off += (size_t)16384 * 2048;
  float* blstm = fws + off; off += (size_t)SEQB * BATCH * HH2;
  float* attnv = fws + off; off += (size_t)SEQB * BATCH;
  float* Hent  = fws + off; off += (size_t)2048 * 512;
  float* Tall  = fws + off; off += (size_t)96 * BATCH * NROWS;
  unsigned long long* hxbuf = (unsigned long long*)(fws + off);
  off += (size_t)2 * 64 * 256 * 2;           // qwords = 2 floats each
  float* Ucat  = fws + off; off += (size_t)NROWS * 512;
  float* WE    = fws + off; off += (size_t)128 * 2048;   // [el][1536 ioc | 512 f]
  float* Mmat  = fws + off; off += 1024;
  float* mbv   = fws + off; off += 16;
  float* hbuf  = fws + off; off += (size_t)1024 * 512;
  const size_t needed = 65536 + off * sizeof(float);
  if (ws_size < needed) return;   // workspace too small: bail (visible failure)

  hipMemsetAsync(d_ws, 0, 65536, stream);
  // hxbuf must start as tag=0/value=0 (valid "h=0 at step 0" records)
  hipMemsetAsync(hxbuf, 0, (size_t)2 * 64 * 256 * 8, stream);

  // 1) Xg = gather(word_emb, tokens) @ [Wih_f;Wih_b].T + [bl_f;bl_b]
  gemm_tn<1, 0><<<dim3(2048 / 128, 16384 / 128), 256, 0, stream>>>(
      nullptr, tokens, word_emb, Wih_f, Wih_b, 1024, bl_f, bl_b, 1024,
      Xg, 16384, 2048, 256);

  // 2) recurrent BiLSTM (quarter-split, tagged h exchange, resident weights)
  lstm_esplit<<<256, 256, 0, stream>>>(Xg, Whh_f, Whh_b, hxbuf, blstm);

  // 3) attention scores + entity H
  attn_k<<<4096, 256, 0, stream>>>(blstm, attn_w, attn_b, attnv);
  entity_prep<<<2048, 64, 0, stream>>>(spans, attnv, blstm, Hent, P_out);

  // 4) DAG-LSTM precompute
  pack_ucat<<<NROWS, 128, 0, stream>>>(U_ioc, Uf, Ucat);
  // WE[el] = [b_ioc + elem_emb[el] @ W_ioc.T | bf + elem_emb[el] @ Wf.T]
  gemm_tn<0, 1><<<dim3(2048 / 128, 1), 256, 0, stream>>>(
      elem_emb, nullptr, nullptr, W_ioc, Wf, 1536, b_ioc, bf, 1536,
      WE, 128, 2048, 128);
  mprep<<<1, 256, 0, stream>>>(W1, b1, W2, b2, Mmat, mbv);
  gemm_tn<0, 0><<<dim3(NROWS / 128, 2048 / 128), 256, 0, stream>>>(
      Hent, nullptr, nullptr, Ucat, nullptr, 0x40000000, nullptr, nullptr, 0,
      Tall, 2048, NROWS, 512);

  // 5) sequential DAG-LSTM with helper projection grid
  dag_seq<<<NHELP + 1, 512, 0, stream>>>(S, T, enames, entsz, WE, Mmat, mbv,
                                         Tall, hbuf, head, slotbase, arrive, Ucat, P_out);
}